// Round 4
// baseline (1317.617 us; speedup 1.0000x reference)
//
#include <hip/hip_runtime.h>
#include <math.h>

#define EPS 1e-5f
#define N_GRAPHS 128

__device__ __forceinline__ float sigmoidf_(float x) {
    return __fdividef(1.0f, 1.0f + __expf(-x));
}

// ---------------------------------------------------------------------------
// Projection kernel v3: register-blocked GEMM, no LDS.
// Thread t -> projection p = t>>6 (k,q,v,s), output col c = t&63.
// Per k-slab (16): weight column slab in VGPRs (coalesced loads, reused 64x);
// x rows are wave-uniform loads (scalarizable to s_load), double-buffered.
// 64 accumulators per thread = 64-node tile. Stores coalesced per wave.
// x may alias AGG (layer-1 in-place): all x loads precede the epilogue
// stores, and each block touches only its own rows.
// ---------------------------------------------------------------------------
template <int IN>
__global__ __launch_bounds__(256) void proj_kernel(
    const float* __restrict__ x,
    const float* __restrict__ Wk, const float* __restrict__ bk,
    const float* __restrict__ Wq, const float* __restrict__ bq,
    const float* __restrict__ Wv, const float* __restrict__ bv,
    const float* __restrict__ Ws, const float* __restrict__ cb,
    float* __restrict__ Aq, float* __restrict__ Av,
    float* __restrict__ Bk, float* __restrict__ AGG,
    int N)
{
    const int t = threadIdx.x;
    const int c = t & 63;
    const int p = __builtin_amdgcn_readfirstlane(t >> 6);  // wave-uniform
    const int n0 = blockIdx.x * 64;

    const float* __restrict__ Wp = (p == 0) ? Wk : (p == 1) ? Wq : (p == 2) ? Wv : Ws;
    const float* __restrict__ bp = (p == 0) ? bk : (p == 1) ? bq : (p == 2) ? bv : cb;
    float* __restrict__ Out      = (p == 0) ? Bk : (p == 1) ? Aq : (p == 2) ? Av : AGG;

    float acc[64];
#pragma unroll
    for (int n = 0; n < 64; ++n) acc[n] = 0.0f;

    for (int k0 = 0; k0 < IN; k0 += 16) {
        // weight column slab: coalesced (consecutive c -> consecutive addr)
        float w[16];
#pragma unroll
        for (int kk = 0; kk < 16; ++kk) w[kk] = Wp[(size_t)(k0 + kk) * 64 + c];

        // x row slab, double-buffered; addresses are thread-uniform
        float4 xa[4], xb[4];
        {
            int row = min(n0, N - 1);
            const float4* __restrict__ xr = (const float4*)(x + (size_t)row * IN + k0);
#pragma unroll
            for (int j = 0; j < 4; ++j) xa[j] = xr[j];
        }
#pragma unroll
        for (int n = 0; n < 64; ++n) {
            int row = min(n0 + n + 1, N - 1);
            const float4* __restrict__ xr = (const float4*)(x + (size_t)row * IN + k0);
#pragma unroll
            for (int j = 0; j < 4; ++j) xb[j] = xr[j];
#pragma unroll
            for (int j = 0; j < 4; ++j) {
                acc[n] = fmaf(xa[j].x, w[4 * j + 0], acc[n]);
                acc[n] = fmaf(xa[j].y, w[4 * j + 1], acc[n]);
                acc[n] = fmaf(xa[j].z, w[4 * j + 2], acc[n]);
                acc[n] = fmaf(xa[j].w, w[4 * j + 3], acc[n]);
            }
#pragma unroll
            for (int j = 0; j < 4; ++j) xa[j] = xb[j];
        }
    }

    const float bias = bp[c];
    const int nn = min(64, N - n0);
#pragma unroll
    for (int n = 0; n < 64; ++n) {
        if (n < nn) Out[(size_t)(n0 + n) * 64 + c] = acc[n] + bias;
    }
}

// ---------------------------------------------------------------------------
// CSR build: degree histogram -> 2-level exclusive scan -> scatter.
// ---------------------------------------------------------------------------
__global__ __launch_bounds__(256) void deg_kernel(
    const int* __restrict__ ei, int* __restrict__ deg, int E)
{
    int t = blockIdx.x * 256 + threadIdx.x;
    int T = gridDim.x * 256;
    for (int e = t; e < E; e += T) atomicAdd(&deg[ei[E + e]], 1);
}

__global__ __launch_bounds__(256) void scan1_kernel(
    const int* __restrict__ deg, int* __restrict__ rp1loc,
    int* __restrict__ psum, int N)
{
    __shared__ int s[256];
    const int b = blockIdx.x;
    const int base = b * 1024;
    const int t = threadIdx.x;
    int v[4], sum = 0;
#pragma unroll
    for (int i = 0; i < 4; ++i) {
        int idx = base + t * 4 + i;
        v[i] = (idx < N) ? deg[idx] : 0;
        sum += v[i];
    }
    s[t] = sum;
    __syncthreads();
    for (int off = 1; off < 256; off <<= 1) {
        int x = (t >= off) ? s[t - off] : 0;
        __syncthreads();
        s[t] += x;
        __syncthreads();
    }
    int run = s[t] - sum;
#pragma unroll
    for (int i = 0; i < 4; ++i) {
        run += v[i];
        int idx = base + t * 4 + i;
        if (idx < N) rp1loc[idx] = run;
    }
    if (t == 255) psum[b] = s[255];
}

__global__ __launch_bounds__(256) void scan2_kernel(int* __restrict__ psum, int NBLK)
{
    __shared__ int s[256];
    int t = threadIdx.x;
    int c = (t < NBLK) ? psum[t] : 0;
    s[t] = c;
    __syncthreads();
    for (int off = 1; off < 256; off <<= 1) {
        int x = (t >= off) ? s[t - off] : 0;
        __syncthreads();
        s[t] += x;
        __syncthreads();
    }
    if (t < NBLK) psum[t] = s[t] - c;
}

__global__ __launch_bounds__(256) void scan3_kernel(
    const int* __restrict__ rp1loc, const int* __restrict__ psum,
    int* __restrict__ rowptr, int* __restrict__ cursor, int N)
{
    int t = blockIdx.x * 256 + threadIdx.x;
    int T = gridDim.x * 256;
    for (int i = t; i < N; i += T) {
        rowptr[i + 1] = rp1loc[i] + psum[i >> 10];
        cursor[i] = (i == 0) ? 0 : rp1loc[i - 1] + psum[(i - 1) >> 10];
    }
    if (t == 0) rowptr[0] = 0;
}

__global__ __launch_bounds__(256) void scatter_kernel(
    const int* __restrict__ ei, int* __restrict__ cursor,
    int* __restrict__ col, int E)
{
    int t = blockIdx.x * 256 + threadIdx.x;
    int T = gridDim.x * 256;
    for (int e = t; e < E; e += T) {
        int d = ei[E + e];
        int pos = atomicAdd(&cursor[d], 1);
        col[pos] = ei[e];
    }
}

// ---------------------------------------------------------------------------
// Aggregation: one dst node per wave (grid-stride), lane = channel. src idx
// loaded coalesced, broadcast via shfl; gathers 4-deep. Epilogue fuses
// sigmoid + BN channel stats.
// ---------------------------------------------------------------------------
__global__ __launch_bounds__(256) void agg_kernel(
    const int* __restrict__ rowptr, const int* __restrict__ col,
    const float* __restrict__ Aq, const float* __restrict__ Av,
    const float* __restrict__ Bk,
    float* __restrict__ AGG, float* __restrict__ stats, int N)
{
    const int tid = threadIdx.x;
    const int lane = tid & 63;
    const int gw = __builtin_amdgcn_readfirstlane(
        (int)((blockIdx.x * blockDim.x + tid) >> 6));
    const int NW = (gridDim.x * blockDim.x) >> 6;

    float st1 = 0.0f, st2 = 0.0f;
    for (int n = gw; n < N; n += NW) {
        int r0 = rowptr[n], r1 = rowptr[n + 1];
        float kk = Bk[(size_t)n * 64 + lane];
        float acc = AGG[(size_t)n * 64 + lane];
        int e = r0;
        while (e < r1) {
            int cnt = min(64, r1 - e);
            int my = (lane < cnt) ? col[e + lane] : 0;
            int j = 0;
            for (; j + 4 <= cnt; j += 4) {
                int s0 = __shfl(my, j);
                int s1 = __shfl(my, j + 1);
                int s2 = __shfl(my, j + 2);
                int s3 = __shfl(my, j + 3);
                float q0 = Aq[(size_t)s0 * 64 + lane];
                float v0 = Av[(size_t)s0 * 64 + lane];
                float q1 = Aq[(size_t)s1 * 64 + lane];
                float v1 = Av[(size_t)s1 * 64 + lane];
                float q2 = Aq[(size_t)s2 * 64 + lane];
                float v2 = Av[(size_t)s2 * 64 + lane];
                float q3 = Aq[(size_t)s3 * 64 + lane];
                float v3 = Av[(size_t)s3 * 64 + lane];
                acc += sigmoidf_(kk + q0) * v0;
                acc += sigmoidf_(kk + q1) * v1;
                acc += sigmoidf_(kk + q2) * v2;
                acc += sigmoidf_(kk + q3) * v3;
            }
            for (; j < cnt; ++j) {
                int s0 = __shfl(my, j);
                float q0 = Aq[(size_t)s0 * 64 + lane];
                float v0 = Av[(size_t)s0 * 64 + lane];
                acc += sigmoidf_(kk + q0) * v0;
            }
            e += cnt;
        }
        float y = sigmoidf_(acc);
        AGG[(size_t)n * 64 + lane] = y;
        st1 += y;
        st2 += y * y;
    }

    __shared__ float red1[4][64], red2[4][64];
    const int w = tid >> 6;
    red1[w][lane] = st1;
    red2[w][lane] = st2;
    __syncthreads();
    if (tid < 64) {
        float a = red1[0][lane] + red1[1][lane] + red1[2][lane] + red1[3][lane];
        float c = red2[0][lane] + red2[1][lane] + red2[2][lane] + red2[3][lane];
        atomicAdd(&stats[lane], a);
        atomicAdd(&stats[64 + lane], c);
    }
}

// ---------------------------------------------------------------------------
// BN-normalize in place + per-graph readout sums (run-length + atomic flush).
// ---------------------------------------------------------------------------
__global__ __launch_bounds__(256) void norm_kernel(
    float* __restrict__ Y, const float* __restrict__ stats,
    const float* __restrict__ g, const float* __restrict__ be,
    const int* __restrict__ batch, float* __restrict__ gsum,
    int N, float invN)
{
    const int lane = threadIdx.x & 63;
    const int gw = (int)((blockIdx.x * blockDim.x + threadIdx.x) >> 6);
    const int NW = (gridDim.x * blockDim.x) >> 6;
    const int chunk = (N + NW - 1) / NW;
    const int nA = gw * chunk;
    const int nB = min(N, nA + chunk);

    float m = stats[lane] * invN;
    float var = stats[64 + lane] * invN - m * m;
    float rs = rsqrtf(var + EPS) * g[lane];
    float bb = be[lane];

    float acc = 0.0f;
    int cur = -1;
    for (int n = nA; n < nB; ++n) {
        int gi = __builtin_amdgcn_readfirstlane(batch[n]);
        float y = Y[(size_t)n * 64 + lane];
        float v = (y - m) * rs + bb;
        Y[(size_t)n * 64 + lane] = v;
        if (gi != cur) {
            if (cur >= 0) atomicAdd(&gsum[cur * 64 + lane], acc);
            acc = 0.0f;
            cur = gi;
        }
        acc += v;
    }
    if (cur >= 0) atomicAdd(&gsum[cur * 64 + lane], acc);
}

__global__ __launch_bounds__(256) void counts_kernel(
    const int* __restrict__ batch, float* __restrict__ counts, int N)
{
    const int t = blockIdx.x * blockDim.x + threadIdx.x;
    const int T = gridDim.x * blockDim.x;
    const int chunk = (N + T - 1) / T;
    const int a = t * chunk;
    const int b = min(N, a + chunk);
    int cur = -1;
    float c = 0.0f;
    for (int n = a; n < b; ++n) {
        int gi = batch[n];
        if (gi != cur) {
            if (cur >= 0) atomicAdd(&counts[cur], c);
            cur = gi;
            c = 0.0f;
        }
        c += 1.0f;
    }
    if (cur >= 0) atomicAdd(&counts[cur], c);
}

// ---------------------------------------------------------------------------
// Head
// ---------------------------------------------------------------------------
__global__ __launch_bounds__(128) void head1_kernel(
    const float* __restrict__ gsum0, const float* __restrict__ gsum1,
    const float* __restrict__ counts,
    const float* __restrict__ Wh0, const float* __restrict__ bh0,
    float* __restrict__ t0, float* __restrict__ hstat0)
{
    const int gr = blockIdx.x;
    const int o = threadIdx.x;
    __shared__ float feat[256];
    float cnt = fmaxf(counts[gr], 1.0f);
    float inv = __fdividef(1.0f, cnt);
    if (o < 64) {
        float s = gsum0[gr * 64 + o];
        feat[o] = s * inv;
        feat[128 + o] = s;
    } else {
        int c = o - 64;
        float s = gsum1[gr * 64 + c];
        feat[64 + c] = s * inv;
        feat[192 + c] = s;
    }
    __syncthreads();
    float acc = bh0[o];
    for (int j = 0; j < 256; ++j) acc = fmaf(feat[j], Wh0[j * 128 + o], acc);
    float y = sigmoidf_(acc);
    t0[gr * 128 + o] = y;
    atomicAdd(&hstat0[o], y);
    atomicAdd(&hstat0[128 + o], y * y);
}

__global__ __launch_bounds__(64) void head2_kernel(
    const float* __restrict__ t0, const float* __restrict__ hstat0,
    const float* __restrict__ gh0, const float* __restrict__ beh0,
    const float* __restrict__ Wh1, const float* __restrict__ bh1,
    float* __restrict__ t1, float* __restrict__ hstat1)
{
    const int gr = blockIdx.x;
    const int o = threadIdx.x;
    __shared__ float bn0[128];
    const float invG = 1.0f / (float)N_GRAPHS;
    for (int j = o; j < 128; j += 64) {
        float m = hstat0[j] * invG;
        float v = hstat0[128 + j] * invG - m * m;
        bn0[j] = (t0[gr * 128 + j] - m) * rsqrtf(v + EPS) * gh0[j] + beh0[j];
    }
    __syncthreads();
    float acc = bh1[o];
    for (int j = 0; j < 128; ++j) acc = fmaf(bn0[j], Wh1[j * 64 + o], acc);
    float y = sigmoidf_(acc);
    t1[gr * 64 + o] = y;
    atomicAdd(&hstat1[o], y);
    atomicAdd(&hstat1[64 + o], y * y);
}

__global__ __launch_bounds__(64) void head3_kernel(
    const float* __restrict__ t1, const float* __restrict__ hstat1,
    const float* __restrict__ gh1, const float* __restrict__ beh1,
    const float* __restrict__ Wc, const float* __restrict__ bc,
    float* __restrict__ out)
{
    const int gr = blockIdx.x;
    const int o = threadIdx.x;
    const float invG = 1.0f / (float)N_GRAPHS;
    float m = hstat1[o] * invG;
    float v = hstat1[64 + o] * invG - m * m;
    float b = (t1[gr * 64 + o] - m) * rsqrtf(v + EPS) * gh1[o] + beh1[o];
    float p0 = b * Wc[o * 2];
    float p1 = b * Wc[o * 2 + 1];
#pragma unroll
    for (int off = 32; off > 0; off >>= 1) {
        p0 += __shfl_down(p0, off);
        p1 += __shfl_down(p1, off);
    }
    if (o == 0) {
        out[gr * 2] = p0 + bc[0];
        out[gr * 2 + 1] = p1 + bc[1];
    }
}

// ---------------------------------------------------------------------------
extern "C" void kernel_launch(void* const* d_in, const int* in_sizes, int n_in,
                              void* d_out, int out_size, void* d_ws, size_t ws_size,
                              hipStream_t stream)
{
    const float* x     = (const float*)d_in[0];
    const int*   ei    = (const int*)d_in[1];
    const int*   batch = (const int*)d_in[2];
    const int N = in_sizes[2];
    const int E = in_sizes[1] / 2;
    const int NCHUNK = (N + 1023) / 1024;

    const float *Wk0 = (const float*)d_in[3],  *bk0 = (const float*)d_in[4];
    const float *Wq0 = (const float*)d_in[5],  *bq0 = (const float*)d_in[6];
    const float *Wv0 = (const float*)d_in[7],  *bv0 = (const float*)d_in[8];
    const float *Ws0 = (const float*)d_in[9],  *cb0 = (const float*)d_in[10];
    const float *g0  = (const float*)d_in[11], *be0 = (const float*)d_in[12];
    const float *Wk1 = (const float*)d_in[13], *bk1 = (const float*)d_in[14];
    const float *Wq1 = (const float*)d_in[15], *bq1 = (const float*)d_in[16];
    const float *Wv1 = (const float*)d_in[17], *bv1 = (const float*)d_in[18];
    const float *Ws1 = (const float*)d_in[19], *cb1 = (const float*)d_in[20];
    const float *g1  = (const float*)d_in[21], *be1 = (const float*)d_in[22];
    const float *Wh0 = (const float*)d_in[23], *bh0 = (const float*)d_in[24];
    const float *gh0 = (const float*)d_in[25], *beh0 = (const float*)d_in[26];
    const float *Wh1 = (const float*)d_in[27], *bh1 = (const float*)d_in[28];
    const float *gh1 = (const float*)d_in[29], *beh1 = (const float*)d_in[30];
    const float *Wc  = (const float*)d_in[31], *bc  = (const float*)d_in[32];

    float* ws = (float*)d_ws;
    float* Aq   = ws;                     // N*64
    float* Av   = Aq + (size_t)N * 64;    // N*64
    float* Bk   = Av + (size_t)N * 64;    // N*64
    float* AGG  = Bk + (size_t)N * 64;    // N*64 (preinit -> y -> BN out, in place)
    int*   col     = (int*)(AGG + (size_t)N * 64);  // E
    int*   rowptr  = col + E;             // N+1
    int*   rp1loc  = rowptr + N + 1;      // N
    int*   cursor  = rp1loc + N;          // N
    int*   psum    = cursor + N;          // 256
    int*   deg     = psum + 256;          // N    <-- zero zone starts here
    float* gsum0  = (float*)(deg + N);    // 128*64
    float* gsum1  = gsum0 + 128 * 64;     // 128*64
    float* counts = gsum1 + 128 * 64;     // 128
    float* stats0 = counts + 128;         // 128
    float* stats1 = stats0 + 128;         // 128
    float* hstat0 = stats1 + 128;         // 256
    float* hstat1 = hstat0 + 256;         // 128
    size_t zbytes = (size_t)N * sizeof(int) +
                    (size_t)(128 * 64 * 2 + 128 * 3 + 256 + 128) * sizeof(float);
    float* t0 = hstat1 + 128;             // 128*128
    float* t1 = t0 + 128 * 128;           // 128*64

    hipMemsetAsync(deg, 0, zbytes, stream);

    // ---- CSR build (shared by both layers) ----
    deg_kernel<<<256, 256, 0, stream>>>(ei, deg, E);
    scan1_kernel<<<NCHUNK, 256, 0, stream>>>(deg, rp1loc, psum, N);
    scan2_kernel<<<1, 256, 0, stream>>>(psum, NCHUNK);
    scan3_kernel<<<256, 256, 0, stream>>>(rp1loc, psum, rowptr, cursor, N);
    scatter_kernel<<<512, 256, 0, stream>>>(ei, cursor, col, E);

    counts_kernel<<<16, 256, 0, stream>>>(batch, counts, N);

    const int projBlocks = (N + 63) / 64;

    // ---- layer 0 ----
    proj_kernel<128><<<projBlocks, 256, 0, stream>>>(
        x, Wk0, bk0, Wq0, bq0, Wv0, bv0, Ws0, cb0, Aq, Av, Bk, AGG, N);
    agg_kernel<<<2048, 256, 0, stream>>>(rowptr, col, Aq, Av, Bk, AGG, stats0, N);
    norm_kernel<<<1024, 256, 0, stream>>>(AGG, stats0, g0, be0, batch, gsum0,
                                          N, 1.0f / (float)N);

    // ---- layer 1 (AGG doubles as X1) ----
    proj_kernel<64><<<projBlocks, 256, 0, stream>>>(
        AGG, Wk1, bk1, Wq1, bq1, Wv1, bv1, Ws1, cb1, Aq, Av, Bk, AGG, N);
    agg_kernel<<<2048, 256, 0, stream>>>(rowptr, col, Aq, Av, Bk, AGG, stats1, N);
    norm_kernel<<<1024, 256, 0, stream>>>(AGG, stats1, g1, be1, batch, gsum1,
                                          N, 1.0f / (float)N);

    // ---- head ----
    head1_kernel<<<128, 128, 0, stream>>>(gsum0, gsum1, counts, Wh0, bh0, t0, hstat0);
    head2_kernel<<<128, 64, 0, stream>>>(t0, hstat0, gh0, beh0, Wh1, bh1, t1, hstat1);
    head3_kernel<<<128, 64, 0, stream>>>(t1, hstat1, gh1, beh1, Wc, bc, (float*)d_out);
}

// Round 5
// 730.463 us; speedup vs baseline: 1.8038x; 1.8038x over previous
//
#include <hip/hip_runtime.h>
#include <math.h>

#define EPS 1e-5f
#define N_GRAPHS 128

__device__ __forceinline__ float sigmoidf_(float x) {
    return __fdividef(1.0f, 1.0f + __expf(-x));
}

// ---------------------------------------------------------------------------
// Weight fusion: Wf[k][c] with c in [0:64)=Wk, [64:128)=Wq, [128:192)=Wv,
// [192:256)=Ws; bf likewise. Run once per layer.
// ---------------------------------------------------------------------------
__global__ __launch_bounds__(256) void fuse_w_kernel(
    const float* __restrict__ Wk, const float* __restrict__ bk,
    const float* __restrict__ Wq, const float* __restrict__ bq,
    const float* __restrict__ Wv, const float* __restrict__ bv,
    const float* __restrict__ Ws, const float* __restrict__ cbv,
    float* __restrict__ Wf, float* __restrict__ bf, int K)
{
    int t = blockIdx.x * 256 + threadIdx.x;
    int total = K * 256;
    for (int i = t; i < total; i += gridDim.x * 256) {
        int k = i >> 8, c = i & 255;
        int p = c >> 6, cc = c & 63;
        const float* W = (p == 0) ? Wk : (p == 1) ? Wq : (p == 2) ? Wv : Ws;
        Wf[i] = W[k * 64 + cc];
    }
    if (t < 256) {
        int p = t >> 6, cc = t & 63;
        const float* b = (p == 0) ? bk : (p == 1) ? bq : (p == 2) ? bv : cbv;
        bf[t] = b[cc];
    }
}

// ---------------------------------------------------------------------------
// Projection v4: LDS-tiled fp32 GEMM  Y[N,256] = X[N,K] @ Wf[K,256] + bf.
// Block: 256 threads; tile M=64 x N=128 (blockIdx&1 picks the N-half).
// Per-thread 8x4 register tile (32 acc -> no spill). K in 16-chunks:
//   As[16][72]  (k-major, transposed at store; float4 reads, broadcast)
//   Bs[16][128] (row-major; 512B contiguous per wave read)
// ---------------------------------------------------------------------------
template <int K>
__global__ __launch_bounds__(256) void proj_kernel(
    const float* __restrict__ X, const float* __restrict__ Wf,
    const float* __restrict__ bf, float* __restrict__ Y, int N)
{
    __shared__ __attribute__((aligned(16))) float As[16][72];
    __shared__ __attribute__((aligned(16))) float Bs[16][128];
    const int tid = threadIdx.x;
    const int nb = blockIdx.x & 1;
    const int n0 = (blockIdx.x >> 1) * 64;
    const int cg = tid & 31;       // 4-col group
    const int mg = tid >> 5;       // 8-row group
    const int ar = tid >> 2, akq = (tid & 3) * 4;     // A staging coords
    const int bk_ = tid >> 4, bcol = (tid & 15) * 8;  // B staging coords

    float acc[8][4];
#pragma unroll
    for (int r = 0; r < 8; ++r)
#pragma unroll
        for (int j = 0; j < 4; ++j) acc[r][j] = 0.0f;

    for (int k0 = 0; k0 < K; k0 += 16) {
        float4 av4 = make_float4(0.f, 0.f, 0.f, 0.f);
        int row = n0 + ar;
        if (row < N) av4 = *(const float4*)&X[(size_t)row * K + k0 + akq];
        const float4 b0 = *(const float4*)&Wf[(size_t)(k0 + bk_) * 256 + nb * 128 + bcol];
        const float4 b1 = *(const float4*)&Wf[(size_t)(k0 + bk_) * 256 + nb * 128 + bcol + 4];
        __syncthreads();
        As[akq + 0][ar] = av4.x;
        As[akq + 1][ar] = av4.y;
        As[akq + 2][ar] = av4.z;
        As[akq + 3][ar] = av4.w;
        *(float4*)&Bs[bk_][bcol] = b0;
        *(float4*)&Bs[bk_][bcol + 4] = b1;
        __syncthreads();
#pragma unroll
        for (int kk = 0; kk < 16; ++kk) {
            float4 a0 = *(const float4*)&As[kk][8 * mg];
            float4 a1 = *(const float4*)&As[kk][8 * mg + 4];
            float4 bv = *(const float4*)&Bs[kk][4 * cg];
            float am[8] = {a0.x, a0.y, a0.z, a0.w, a1.x, a1.y, a1.z, a1.w};
#pragma unroll
            for (int r = 0; r < 8; ++r) {
                acc[r][0] = fmaf(am[r], bv.x, acc[r][0]);
                acc[r][1] = fmaf(am[r], bv.y, acc[r][1]);
                acc[r][2] = fmaf(am[r], bv.z, acc[r][2]);
                acc[r][3] = fmaf(am[r], bv.w, acc[r][3]);
            }
        }
    }

    float4 bias;
    bias.x = bf[nb * 128 + 4 * cg + 0];
    bias.y = bf[nb * 128 + 4 * cg + 1];
    bias.z = bf[nb * 128 + 4 * cg + 2];
    bias.w = bf[nb * 128 + 4 * cg + 3];
#pragma unroll
    for (int r = 0; r < 8; ++r) {
        int row = n0 + 8 * mg + r;
        if (row < N) {
            float4 o;
            o.x = acc[r][0] + bias.x;
            o.y = acc[r][1] + bias.y;
            o.z = acc[r][2] + bias.z;
            o.w = acc[r][3] + bias.w;
            *(float4*)&Y[(size_t)row * 256 + nb * 128 + 4 * cg] = o;
        }
    }
}

// ---------------------------------------------------------------------------
// CSR build: degree histogram -> 2-level exclusive scan -> scatter.
// ---------------------------------------------------------------------------
__global__ __launch_bounds__(256) void deg_kernel(
    const int* __restrict__ ei, int* __restrict__ deg, int E)
{
    int t = blockIdx.x * 256 + threadIdx.x;
    int T = gridDim.x * 256;
    for (int e = t; e < E; e += T) atomicAdd(&deg[ei[E + e]], 1);
}

__global__ __launch_bounds__(256) void scan1_kernel(
    const int* __restrict__ deg, int* __restrict__ rp1loc,
    int* __restrict__ psum, int N)
{
    __shared__ int s[256];
    const int b = blockIdx.x;
    const int base = b * 1024;
    const int t = threadIdx.x;
    int v[4], sum = 0;
#pragma unroll
    for (int i = 0; i < 4; ++i) {
        int idx = base + t * 4 + i;
        v[i] = (idx < N) ? deg[idx] : 0;
        sum += v[i];
    }
    s[t] = sum;
    __syncthreads();
    for (int off = 1; off < 256; off <<= 1) {
        int x = (t >= off) ? s[t - off] : 0;
        __syncthreads();
        s[t] += x;
        __syncthreads();
    }
    int run = s[t] - sum;
#pragma unroll
    for (int i = 0; i < 4; ++i) {
        run += v[i];
        int idx = base + t * 4 + i;
        if (idx < N) rp1loc[idx] = run;
    }
    if (t == 255) psum[b] = s[255];
}

__global__ __launch_bounds__(256) void scan2_kernel(int* __restrict__ psum, int NBLK)
{
    __shared__ int s[256];
    int t = threadIdx.x;
    int c = (t < NBLK) ? psum[t] : 0;
    s[t] = c;
    __syncthreads();
    for (int off = 1; off < 256; off <<= 1) {
        int x = (t >= off) ? s[t - off] : 0;
        __syncthreads();
        s[t] += x;
        __syncthreads();
    }
    if (t < NBLK) psum[t] = s[t] - c;
}

__global__ __launch_bounds__(256) void scan3_kernel(
    const int* __restrict__ rp1loc, const int* __restrict__ psum,
    int* __restrict__ rowptr, int* __restrict__ cursor, int N)
{
    int t = blockIdx.x * 256 + threadIdx.x;
    int T = gridDim.x * 256;
    for (int i = t; i < N; i += T) {
        rowptr[i + 1] = rp1loc[i] + psum[i >> 10];
        cursor[i] = (i == 0) ? 0 : rp1loc[i - 1] + psum[(i - 1) >> 10];
    }
    if (t == 0) rowptr[0] = 0;
}

__global__ __launch_bounds__(256) void scatter_kernel(
    const int* __restrict__ ei, int* __restrict__ cursor,
    int* __restrict__ col, int E)
{
    int t = blockIdx.x * 256 + threadIdx.x;
    int T = gridDim.x * 256;
    for (int e = t; e < E; e += T) {
        int d = ei[E + e];
        int pos = atomicAdd(&cursor[d], 1);
        col[pos] = ei[e];
    }
}

// ---------------------------------------------------------------------------
// Aggregation: one dst node per wave (grid-stride), lane = channel; reads the
// fused Y rows: k=Y[n][lane], q=Y[s][64+lane], v=Y[s][128+lane],
// preinit=Y[n][192+lane]. Writes H[n][lane]. Fuses sigmoid + BN stats.
// ---------------------------------------------------------------------------
__global__ __launch_bounds__(256) void agg_kernel(
    const int* __restrict__ rowptr, const int* __restrict__ col,
    const float* __restrict__ Y, float* __restrict__ H,
    float* __restrict__ stats, int N)
{
    const int tid = threadIdx.x;
    const int lane = tid & 63;
    const int gw = __builtin_amdgcn_readfirstlane(
        (int)((blockIdx.x * blockDim.x + tid) >> 6));
    const int NW = (gridDim.x * blockDim.x) >> 6;

    float st1 = 0.0f, st2 = 0.0f;
    for (int n = gw; n < N; n += NW) {
        int r0 = rowptr[n], r1 = rowptr[n + 1];
        float kk = Y[(size_t)n * 256 + lane];
        float acc = Y[(size_t)n * 256 + 192 + lane];
        int e = r0;
        while (e < r1) {
            int cnt = min(64, r1 - e);
            int my = (lane < cnt) ? col[e + lane] : 0;
            int j = 0;
            for (; j + 4 <= cnt; j += 4) {
                int s0 = __shfl(my, j);
                int s1 = __shfl(my, j + 1);
                int s2 = __shfl(my, j + 2);
                int s3 = __shfl(my, j + 3);
                float q0 = Y[(size_t)s0 * 256 + 64 + lane];
                float v0 = Y[(size_t)s0 * 256 + 128 + lane];
                float q1 = Y[(size_t)s1 * 256 + 64 + lane];
                float v1 = Y[(size_t)s1 * 256 + 128 + lane];
                float q2 = Y[(size_t)s2 * 256 + 64 + lane];
                float v2 = Y[(size_t)s2 * 256 + 128 + lane];
                float q3 = Y[(size_t)s3 * 256 + 64 + lane];
                float v3 = Y[(size_t)s3 * 256 + 128 + lane];
                acc += sigmoidf_(kk + q0) * v0;
                acc += sigmoidf_(kk + q1) * v1;
                acc += sigmoidf_(kk + q2) * v2;
                acc += sigmoidf_(kk + q3) * v3;
            }
            for (; j < cnt; ++j) {
                int s0 = __shfl(my, j);
                float q0 = Y[(size_t)s0 * 256 + 64 + lane];
                float v0 = Y[(size_t)s0 * 256 + 128 + lane];
                acc += sigmoidf_(kk + q0) * v0;
            }
            e += cnt;
        }
        float y = sigmoidf_(acc);
        H[(size_t)n * 64 + lane] = y;
        st1 += y;
        st2 += y * y;
    }

    __shared__ float red1[4][64], red2[4][64];
    const int w = tid >> 6;
    red1[w][lane] = st1;
    red2[w][lane] = st2;
    __syncthreads();
    if (tid < 64) {
        float a = red1[0][lane] + red1[1][lane] + red1[2][lane] + red1[3][lane];
        float c = red2[0][lane] + red2[1][lane] + red2[2][lane] + red2[3][lane];
        atomicAdd(&stats[lane], a);
        atomicAdd(&stats[64 + lane], c);
    }
}

// ---------------------------------------------------------------------------
// BN-normalize in place + per-graph readout sums (run-length + atomic flush).
// ---------------------------------------------------------------------------
__global__ __launch_bounds__(256) void norm_kernel(
    float* __restrict__ H, const float* __restrict__ stats,
    const float* __restrict__ g, const float* __restrict__ be,
    const int* __restrict__ batch, float* __restrict__ gsum,
    int N, float invN)
{
    const int lane = threadIdx.x & 63;
    const int gw = (int)((blockIdx.x * blockDim.x + threadIdx.x) >> 6);
    const int NW = (gridDim.x * blockDim.x) >> 6;
    const int chunk = (N + NW - 1) / NW;
    const int nA = gw * chunk;
    const int nB = min(N, nA + chunk);

    float m = stats[lane] * invN;
    float var = stats[64 + lane] * invN - m * m;
    float rs = rsqrtf(var + EPS) * g[lane];
    float bb = be[lane];

    float acc = 0.0f;
    int cur = -1;
    for (int n = nA; n < nB; ++n) {
        int gi = __builtin_amdgcn_readfirstlane(batch[n]);
        float y = H[(size_t)n * 64 + lane];
        float v = (y - m) * rs + bb;
        H[(size_t)n * 64 + lane] = v;
        if (gi != cur) {
            if (cur >= 0) atomicAdd(&gsum[cur * 64 + lane], acc);
            acc = 0.0f;
            cur = gi;
        }
        acc += v;
    }
    if (cur >= 0) atomicAdd(&gsum[cur * 64 + lane], acc);
}

__global__ __launch_bounds__(256) void counts_kernel(
    const int* __restrict__ batch, float* __restrict__ counts, int N)
{
    const int t = blockIdx.x * blockDim.x + threadIdx.x;
    const int T = gridDim.x * blockDim.x;
    const int chunk = (N + T - 1) / T;
    const int a = t * chunk;
    const int b = min(N, a + chunk);
    int cur = -1;
    float c = 0.0f;
    for (int n = a; n < b; ++n) {
        int gi = batch[n];
        if (gi != cur) {
            if (cur >= 0) atomicAdd(&counts[cur], c);
            cur = gi;
            c = 0.0f;
        }
        c += 1.0f;
    }
    if (cur >= 0) atomicAdd(&counts[cur], c);
}

// ---------------------------------------------------------------------------
// Head
// ---------------------------------------------------------------------------
__global__ __launch_bounds__(128) void head1_kernel(
    const float* __restrict__ gsum0, const float* __restrict__ gsum1,
    const float* __restrict__ counts,
    const float* __restrict__ Wh0, const float* __restrict__ bh0,
    float* __restrict__ t0, float* __restrict__ hstat0)
{
    const int gr = blockIdx.x;
    const int o = threadIdx.x;
    __shared__ float feat[256];
    float cnt = fmaxf(counts[gr], 1.0f);
    float inv = __fdividef(1.0f, cnt);
    if (o < 64) {
        float s = gsum0[gr * 64 + o];
        feat[o] = s * inv;
        feat[128 + o] = s;
    } else {
        int c = o - 64;
        float s = gsum1[gr * 64 + c];
        feat[64 + c] = s * inv;
        feat[192 + c] = s;
    }
    __syncthreads();
    float acc = bh0[o];
    for (int j = 0; j < 256; ++j) acc = fmaf(feat[j], Wh0[j * 128 + o], acc);
    float y = sigmoidf_(acc);
    t0[gr * 128 + o] = y;
    atomicAdd(&hstat0[o], y);
    atomicAdd(&hstat0[128 + o], y * y);
}

__global__ __launch_bounds__(64) void head2_kernel(
    const float* __restrict__ t0, const float* __restrict__ hstat0,
    const float* __restrict__ gh0, const float* __restrict__ beh0,
    const float* __restrict__ Wh1, const float* __restrict__ bh1,
    float* __restrict__ t1, float* __restrict__ hstat1)
{
    const int gr = blockIdx.x;
    const int o = threadIdx.x;
    __shared__ float bn0[128];
    const float invG = 1.0f / (float)N_GRAPHS;
    for (int j = o; j < 128; j += 64) {
        float m = hstat0[j] * invG;
        float v = hstat0[128 + j] * invG - m * m;
        bn0[j] = (t0[gr * 128 + j] - m) * rsqrtf(v + EPS) * gh0[j] + beh0[j];
    }
    __syncthreads();
    float acc = bh1[o];
    for (int j = 0; j < 128; ++j) acc = fmaf(bn0[j], Wh1[j * 64 + o], acc);
    float y = sigmoidf_(acc);
    t1[gr * 64 + o] = y;
    atomicAdd(&hstat1[o], y);
    atomicAdd(&hstat1[64 + o], y * y);
}

__global__ __launch_bounds__(64) void head3_kernel(
    const float* __restrict__ t1, const float* __restrict__ hstat1,
    const float* __restrict__ gh1, const float* __restrict__ beh1,
    const float* __restrict__ Wc, const float* __restrict__ bc,
    float* __restrict__ out)
{
    const int gr = blockIdx.x;
    const int o = threadIdx.x;
    const float invG = 1.0f / (float)N_GRAPHS;
    float m = hstat1[o] * invG;
    float v = hstat1[64 + o] * invG - m * m;
    float b = (t1[gr * 64 + o] - m) * rsqrtf(v + EPS) * gh1[o] + beh1[o];
    float p0 = b * Wc[o * 2];
    float p1 = b * Wc[o * 2 + 1];
#pragma unroll
    for (int off = 32; off > 0; off >>= 1) {
        p0 += __shfl_down(p0, off);
        p1 += __shfl_down(p1, off);
    }
    if (o == 0) {
        out[gr * 2] = p0 + bc[0];
        out[gr * 2 + 1] = p1 + bc[1];
    }
}

// ---------------------------------------------------------------------------
extern "C" void kernel_launch(void* const* d_in, const int* in_sizes, int n_in,
                              void* d_out, int out_size, void* d_ws, size_t ws_size,
                              hipStream_t stream)
{
    const float* x     = (const float*)d_in[0];
    const int*   ei    = (const int*)d_in[1];
    const int*   batch = (const int*)d_in[2];
    const int N = in_sizes[2];
    const int E = in_sizes[1] / 2;
    const int NCHUNK = (N + 1023) / 1024;

    const float *Wk0 = (const float*)d_in[3],  *bk0 = (const float*)d_in[4];
    const float *Wq0 = (const float*)d_in[5],  *bq0 = (const float*)d_in[6];
    const float *Wv0 = (const float*)d_in[7],  *bv0 = (const float*)d_in[8];
    const float *Ws0 = (const float*)d_in[9],  *cb0 = (const float*)d_in[10];
    const float *g0  = (const float*)d_in[11], *be0 = (const float*)d_in[12];
    const float *Wk1 = (const float*)d_in[13], *bk1 = (const float*)d_in[14];
    const float *Wq1 = (const float*)d_in[15], *bq1 = (const float*)d_in[16];
    const float *Wv1 = (const float*)d_in[17], *bv1 = (const float*)d_in[18];
    const float *Ws1 = (const float*)d_in[19], *cb1 = (const float*)d_in[20];
    const float *g1  = (const float*)d_in[21], *be1 = (const float*)d_in[22];
    const float *Wh0 = (const float*)d_in[23], *bh0 = (const float*)d_in[24];
    const float *gh0 = (const float*)d_in[25], *beh0 = (const float*)d_in[26];
    const float *Wh1 = (const float*)d_in[27], *bh1 = (const float*)d_in[28];
    const float *gh1 = (const float*)d_in[29], *beh1 = (const float*)d_in[30];
    const float *Wc  = (const float*)d_in[31], *bc  = (const float*)d_in[32];

    float* ws = (float*)d_ws;
    float* Y    = ws;                     // N*256 fused [k|q|v|s]
    float* H    = Y + (size_t)N * 256;    // N*64  (agg out -> BN in place -> next X)
    int*   col     = (int*)(H + (size_t)N * 64);    // E
    int*   rowptr  = col + E;             // N+1
    int*   rp1loc  = rowptr + N + 1;      // N
    int*   cursor  = rp1loc + N;          // N
    int*   psum    = cursor + N;          // 256
    float* Wf0  = (float*)(psum + 256);   // 128*256
    float* bf0  = Wf0 + 128 * 256;        // 256
    float* Wf1  = bf0 + 256;              // 64*256
    float* bf1  = Wf1 + 64 * 256;         // 256
    int*   deg     = (int*)(bf1 + 256);   // N    <-- zero zone starts here
    float* gsum0  = (float*)(deg + N);    // 128*64
    float* gsum1  = gsum0 + 128 * 64;     // 128*64
    float* counts = gsum1 + 128 * 64;     // 128
    float* stats0 = counts + 128;         // 128
    float* stats1 = stats0 + 128;         // 128
    float* hstat0 = stats1 + 128;         // 256
    float* hstat1 = hstat0 + 256;         // 128
    size_t zbytes = (size_t)N * sizeof(int) +
                    (size_t)(128 * 64 * 2 + 128 * 3 + 256 + 128) * sizeof(float);
    float* t0 = hstat1 + 128;             // 128*128
    float* t1 = t0 + 128 * 128;           // 128*64

    hipMemsetAsync(deg, 0, zbytes, stream);

    // ---- CSR build + weight fusion (shared / once) ----
    deg_kernel<<<256, 256, 0, stream>>>(ei, deg, E);
    scan1_kernel<<<NCHUNK, 256, 0, stream>>>(deg, rp1loc, psum, N);
    scan2_kernel<<<1, 256, 0, stream>>>(psum, NCHUNK);
    scan3_kernel<<<256, 256, 0, stream>>>(rp1loc, psum, rowptr, cursor, N);
    scatter_kernel<<<512, 256, 0, stream>>>(ei, cursor, col, E);
    fuse_w_kernel<<<64, 256, 0, stream>>>(Wk0, bk0, Wq0, bq0, Wv0, bv0, Ws0, cb0,
                                          Wf0, bf0, 128);
    fuse_w_kernel<<<64, 256, 0, stream>>>(Wk1, bk1, Wq1, bq1, Wv1, bv1, Ws1, cb1,
                                          Wf1, bf1, 64);
    counts_kernel<<<16, 256, 0, stream>>>(batch, counts, N);

    const int projBlocks = ((N + 63) / 64) * 2;

    // ---- layer 0 ----
    proj_kernel<128><<<projBlocks, 256, 0, stream>>>(x, Wf0, bf0, Y, N);
    agg_kernel<<<2048, 256, 0, stream>>>(rowptr, col, Y, H, stats0, N);
    norm_kernel<<<1024, 256, 0, stream>>>(H, stats0, g0, be0, batch, gsum0,
                                          N, 1.0f / (float)N);

    // ---- layer 1 ----
    proj_kernel<64><<<projBlocks, 256, 0, stream>>>(H, Wf1, bf1, Y, N);
    agg_kernel<<<2048, 256, 0, stream>>>(rowptr, col, Y, H, stats1, N);
    norm_kernel<<<1024, 256, 0, stream>>>(H, stats1, g1, be1, batch, gsum1,
                                          N, 1.0f / (float)N);

    // ---- head ----
    head1_kernel<<<128, 128, 0, stream>>>(gsum0, gsum1, counts, Wh0, bh0, t0, hstat0);
    head2_kernel<<<128, 64, 0, stream>>>(t0, hstat0, gh0, beh0, Wh1, bh1, t1, hstat1);
    head3_kernel<<<128, 64, 0, stream>>>(t1, hstat1, gh1, beh1, Wc, bc, (float*)d_out);
}

// Round 6
// 696.688 us; speedup vs baseline: 1.8913x; 1.0485x over previous
//
#include <hip/hip_runtime.h>
#include <hip/hip_fp16.h>
#include <math.h>

#define EPS 1e-5f
#define N_GRAPHS 128

__device__ __forceinline__ float sigmoidf_(float x) {
    return __fdividef(1.0f, 1.0f + __expf(-x));
}

// ---------------------------------------------------------------------------
// Weight fusion with column permutation. Fused col c:
//   [0,64)    = Wk col c        (k, fp32 out)
//   [64,128)  = Ws col c-64     (s/preinit, fp32 out)
//   [128,256) = interleaved q,v: j=c-128, channel=j>>1, j&1 ? Wv : Wq
// bf likewise. Run once per layer.
// ---------------------------------------------------------------------------
__global__ __launch_bounds__(256) void fuse_w_kernel(
    const float* __restrict__ Wk, const float* __restrict__ bk,
    const float* __restrict__ Wq, const float* __restrict__ bq,
    const float* __restrict__ Wv, const float* __restrict__ bv,
    const float* __restrict__ Ws, const float* __restrict__ cbv,
    float* __restrict__ Wf, float* __restrict__ bf, int K)
{
    int t = blockIdx.x * 256 + threadIdx.x;
    int total = K * 256;
    for (int i = t; i < total; i += gridDim.x * 256) {
        int k = i >> 8, c = i & 255;
        const float* W;
        int cc;
        if (c < 64)       { W = Wk; cc = c; }
        else if (c < 128) { W = Ws; cc = c - 64; }
        else { int j = c - 128; cc = j >> 1; W = (j & 1) ? Wv : Wq; }
        Wf[i] = W[k * 64 + cc];
    }
    if (t < 256) {
        int c = t;
        const float* b;
        int cc;
        if (c < 64)       { b = bk;  cc = c; }
        else if (c < 128) { b = cbv; cc = c - 64; }
        else { int j = c - 128; cc = j >> 1; b = (j & 1) ? bv : bq; }
        bf[t] = b[cc];
    }
}

// ---------------------------------------------------------------------------
// BN affine precompute: Aaff[c]=rs, Baff[c]=be-m*rs  (v = h*A + B).
// ---------------------------------------------------------------------------
__global__ __launch_bounds__(64) void prep_affine_kernel(
    const float* __restrict__ stats, const float* __restrict__ g,
    const float* __restrict__ be, float* __restrict__ Aaff,
    float* __restrict__ Baff, float invN)
{
    int c = threadIdx.x;
    float m = stats[c] * invN;
    float var = stats[64 + c] * invN - m * m;
    float rs = rsqrtf(var + EPS) * g[c];
    Aaff[c] = rs;
    Baff[c] = be[c] - m * rs;
}

// ---------------------------------------------------------------------------
// Projection: LDS-tiled fp32 GEMM, fused cols. Block: 256 thr; tile M=64 x
// N=128 (blockIdx&1 = nb). Per-thread 8x4 acc (no spill).
// nb=0 -> fp32 [k|s] to Y2[N][128]; nb=1 -> fp16-packed (q,v) to QV[N][64].
// AFF: apply BN affine (per input column) while staging X.
// ---------------------------------------------------------------------------
template <int K, bool AFF>
__global__ __launch_bounds__(256) void proj_kernel(
    const float* __restrict__ X, const float* __restrict__ Wf,
    const float* __restrict__ bf,
    const float* __restrict__ Aaff, const float* __restrict__ Baff,
    float* __restrict__ Y2, unsigned* __restrict__ QV, int N)
{
    __shared__ __attribute__((aligned(16))) float As[16][72];
    __shared__ __attribute__((aligned(16))) float Bs[16][128];
    const int tid = threadIdx.x;
    const int nb = blockIdx.x & 1;
    const int n0 = (blockIdx.x >> 1) * 64;
    const int cg = tid & 31;
    const int mg = tid >> 5;
    const int ar = tid >> 2, akq = (tid & 3) * 4;
    const int bk_ = tid >> 4, bcol = (tid & 15) * 8;

    float acc[8][4];
#pragma unroll
    for (int r = 0; r < 8; ++r)
#pragma unroll
        for (int j = 0; j < 4; ++j) acc[r][j] = 0.0f;

    for (int k0 = 0; k0 < K; k0 += 16) {
        float4 av4 = make_float4(0.f, 0.f, 0.f, 0.f);
        int row = n0 + ar;
        if (row < N) av4 = *(const float4*)&X[(size_t)row * K + k0 + akq];
        if constexpr (AFF) {
            float4 Aa = *(const float4*)&Aaff[k0 + akq];
            float4 Bb = *(const float4*)&Baff[k0 + akq];
            av4.x = fmaf(av4.x, Aa.x, Bb.x);
            av4.y = fmaf(av4.y, Aa.y, Bb.y);
            av4.z = fmaf(av4.z, Aa.z, Bb.z);
            av4.w = fmaf(av4.w, Aa.w, Bb.w);
        }
        const float4 b0 = *(const float4*)&Wf[(size_t)(k0 + bk_) * 256 + nb * 128 + bcol];
        const float4 b1 = *(const float4*)&Wf[(size_t)(k0 + bk_) * 256 + nb * 128 + bcol + 4];
        __syncthreads();
        As[akq + 0][ar] = av4.x;
        As[akq + 1][ar] = av4.y;
        As[akq + 2][ar] = av4.z;
        As[akq + 3][ar] = av4.w;
        *(float4*)&Bs[bk_][bcol] = b0;
        *(float4*)&Bs[bk_][bcol + 4] = b1;
        __syncthreads();
#pragma unroll
        for (int kk = 0; kk < 16; ++kk) {
            float4 a0 = *(const float4*)&As[kk][8 * mg];
            float4 a1 = *(const float4*)&As[kk][8 * mg + 4];
            float4 bv = *(const float4*)&Bs[kk][4 * cg];
            float am[8] = {a0.x, a0.y, a0.z, a0.w, a1.x, a1.y, a1.z, a1.w};
#pragma unroll
            for (int r = 0; r < 8; ++r) {
                acc[r][0] = fmaf(am[r], bv.x, acc[r][0]);
                acc[r][1] = fmaf(am[r], bv.y, acc[r][1]);
                acc[r][2] = fmaf(am[r], bv.z, acc[r][2]);
                acc[r][3] = fmaf(am[r], bv.w, acc[r][3]);
            }
        }
    }

    float4 bias;
    bias.x = bf[nb * 128 + 4 * cg + 0];
    bias.y = bf[nb * 128 + 4 * cg + 1];
    bias.z = bf[nb * 128 + 4 * cg + 2];
    bias.w = bf[nb * 128 + 4 * cg + 3];
    const int nn = min(64, N - n0);
    if (nb == 0) {
#pragma unroll
        for (int r = 0; r < 8; ++r) {
            int row = 8 * mg + r;
            if (row < nn) {
                float4 o;
                o.x = acc[r][0] + bias.x;
                o.y = acc[r][1] + bias.y;
                o.z = acc[r][2] + bias.z;
                o.w = acc[r][3] + bias.w;
                *(float4*)&Y2[(size_t)(n0 + row) * 128 + 4 * cg] = o;
            }
        }
    } else {
#pragma unroll
        for (int r = 0; r < 8; ++r) {
            int row = 8 * mg + r;
            if (row < nn) {
                __half2 p0 = __floats2half2_rn(acc[r][0] + bias.x, acc[r][1] + bias.y);
                __half2 p1 = __floats2half2_rn(acc[r][2] + bias.z, acc[r][3] + bias.w);
                uint2 u;
                u.x = *reinterpret_cast<unsigned*>(&p0);
                u.y = *reinterpret_cast<unsigned*>(&p1);
                *(uint2*)&QV[(size_t)(n0 + row) * 64 + 2 * cg] = u;
            }
        }
    }
}

// ---------------------------------------------------------------------------
// CSR build: degree histogram -> 2-level exclusive scan -> scatter.
// ---------------------------------------------------------------------------
__global__ __launch_bounds__(256) void deg_kernel(
    const int* __restrict__ ei, int* __restrict__ deg, int E)
{
    int t = blockIdx.x * 256 + threadIdx.x;
    int T = gridDim.x * 256;
    for (int e = t; e < E; e += T) atomicAdd(&deg[ei[E + e]], 1);
}

__global__ __launch_bounds__(256) void scan1_kernel(
    const int* __restrict__ deg, int* __restrict__ rp1loc,
    int* __restrict__ psum, int N)
{
    __shared__ int s[256];
    const int b = blockIdx.x;
    const int base = b * 1024;
    const int t = threadIdx.x;
    int v[4], sum = 0;
#pragma unroll
    for (int i = 0; i < 4; ++i) {
        int idx = base + t * 4 + i;
        v[i] = (idx < N) ? deg[idx] : 0;
        sum += v[i];
    }
    s[t] = sum;
    __syncthreads();
    for (int off = 1; off < 256; off <<= 1) {
        int x = (t >= off) ? s[t - off] : 0;
        __syncthreads();
        s[t] += x;
        __syncthreads();
    }
    int run = s[t] - sum;
#pragma unroll
    for (int i = 0; i < 4; ++i) {
        run += v[i];
        int idx = base + t * 4 + i;
        if (idx < N) rp1loc[idx] = run;
    }
    if (t == 255) psum[b] = s[255];
}

__global__ __launch_bounds__(256) void scan2_kernel(int* __restrict__ psum, int NBLK)
{
    __shared__ int s[256];
    int t = threadIdx.x;
    int c = (t < NBLK) ? psum[t] : 0;
    s[t] = c;
    __syncthreads();
    for (int off = 1; off < 256; off <<= 1) {
        int x = (t >= off) ? s[t - off] : 0;
        __syncthreads();
        s[t] += x;
        __syncthreads();
    }
    if (t < NBLK) psum[t] = s[t] - c;
}

__global__ __launch_bounds__(256) void scan3_kernel(
    const int* __restrict__ rp1loc, const int* __restrict__ psum,
    int* __restrict__ rowptr, int* __restrict__ cursor, int N)
{
    int t = blockIdx.x * 256 + threadIdx.x;
    int T = gridDim.x * 256;
    for (int i = t; i < N; i += T) {
        rowptr[i + 1] = rp1loc[i] + psum[i >> 10];
        cursor[i] = (i == 0) ? 0 : rp1loc[i - 1] + psum[(i - 1) >> 10];
    }
    if (t == 0) rowptr[0] = 0;
}

__global__ __launch_bounds__(256) void scatter_kernel(
    const int* __restrict__ ei, int* __restrict__ cursor,
    int* __restrict__ col, int E)
{
    int t = blockIdx.x * 256 + threadIdx.x;
    int T = gridDim.x * 256;
    for (int e = t; e < E; e += T) {
        int d = ei[E + e];
        int pos = atomicAdd(&cursor[d], 1);
        col[pos] = ei[e];
    }
}

// ---------------------------------------------------------------------------
// Aggregation: one dst node per wave, lane = channel. k/preinit from fp32
// Y2[n][128]; per-edge gather = ONE dword from QV (fp16 q|v). Fuses sigmoid
// + BN channel stats. H out fp32.
// ---------------------------------------------------------------------------
__global__ __launch_bounds__(256) void agg_kernel(
    const int* __restrict__ rowptr, const int* __restrict__ col,
    const float* __restrict__ Y2, const unsigned* __restrict__ QV,
    float* __restrict__ H, float* __restrict__ stats, int N)
{
    const int tid = threadIdx.x;
    const int lane = tid & 63;
    const int gw = __builtin_amdgcn_readfirstlane(
        (int)((blockIdx.x * blockDim.x + tid) >> 6));
    const int NW = (gridDim.x * blockDim.x) >> 6;

    float st1 = 0.0f, st2 = 0.0f;
    for (int n = gw; n < N; n += NW) {
        int r0 = rowptr[n], r1 = rowptr[n + 1];
        float kk = Y2[(size_t)n * 128 + lane];
        float acc = Y2[(size_t)n * 128 + 64 + lane];
        int e = r0;
        while (e < r1) {
            int cnt = min(64, r1 - e);
            int my = (lane < cnt) ? col[e + lane] : 0;
            int j = 0;
            for (; j + 4 <= cnt; j += 4) {
                int s0 = __shfl(my, j);
                int s1 = __shfl(my, j + 1);
                int s2 = __shfl(my, j + 2);
                int s3 = __shfl(my, j + 3);
                unsigned u0 = QV[(size_t)s0 * 64 + lane];
                unsigned u1 = QV[(size_t)s1 * 64 + lane];
                unsigned u2 = QV[(size_t)s2 * 64 + lane];
                unsigned u3 = QV[(size_t)s3 * 64 + lane];
                float2 f0 = __half22float2(*reinterpret_cast<__half2*>(&u0));
                float2 f1 = __half22float2(*reinterpret_cast<__half2*>(&u1));
                float2 f2 = __half22float2(*reinterpret_cast<__half2*>(&u2));
                float2 f3 = __half22float2(*reinterpret_cast<__half2*>(&u3));
                acc += sigmoidf_(kk + f0.x) * f0.y;
                acc += sigmoidf_(kk + f1.x) * f1.y;
                acc += sigmoidf_(kk + f2.x) * f2.y;
                acc += sigmoidf_(kk + f3.x) * f3.y;
            }
            for (; j < cnt; ++j) {
                int s0 = __shfl(my, j);
                unsigned u0 = QV[(size_t)s0 * 64 + lane];
                float2 f0 = __half22float2(*reinterpret_cast<__half2*>(&u0));
                acc += sigmoidf_(kk + f0.x) * f0.y;
            }
            e += cnt;
        }
        float y = sigmoidf_(acc);
        H[(size_t)n * 64 + lane] = y;
        st1 += y;
        st2 += y * y;
    }

    __shared__ float red1[4][64], red2[4][64];
    const int w = tid >> 6;
    red1[w][lane] = st1;
    red2[w][lane] = st2;
    __syncthreads();
    if (tid < 64) {
        float a = red1[0][lane] + red1[1][lane] + red1[2][lane] + red1[3][lane];
        float c = red2[0][lane] + red2[1][lane] + red2[2][lane] + red2[3][lane];
        atomicAdd(&stats[lane], a);
        atomicAdd(&stats[64 + lane], c);
    }
}

// ---------------------------------------------------------------------------
// Readout: BN-normalize in registers (no write-back) + per-graph sums.
// ---------------------------------------------------------------------------
__global__ __launch_bounds__(256) void readout_kernel(
    const float* __restrict__ H, const float* __restrict__ stats,
    const float* __restrict__ g, const float* __restrict__ be,
    const int* __restrict__ batch, float* __restrict__ gsum,
    int N, float invN)
{
    const int lane = threadIdx.x & 63;
    const int gw = (int)((blockIdx.x * blockDim.x + threadIdx.x) >> 6);
    const int NW = (gridDim.x * blockDim.x) >> 6;
    const int chunk = (N + NW - 1) / NW;
    const int nA = gw * chunk;
    const int nB = min(N, nA + chunk);

    float m = stats[lane] * invN;
    float var = stats[64 + lane] * invN - m * m;
    float rs = rsqrtf(var + EPS) * g[lane];
    float bb = be[lane];

    float acc = 0.0f;
    int cur = -1;
    for (int n = nA; n < nB; ++n) {
        int gi = __builtin_amdgcn_readfirstlane(batch[n]);
        float y = H[(size_t)n * 64 + lane];
        float v = (y - m) * rs + bb;
        if (gi != cur) {
            if (cur >= 0) atomicAdd(&gsum[cur * 64 + lane], acc);
            acc = 0.0f;
            cur = gi;
        }
        acc += v;
    }
    if (cur >= 0) atomicAdd(&gsum[cur * 64 + lane], acc);
}

__global__ __launch_bounds__(256) void counts_kernel(
    const int* __restrict__ batch, float* __restrict__ counts, int N)
{
    const int t = blockIdx.x * blockDim.x + threadIdx.x;
    const int T = gridDim.x * blockDim.x;
    const int chunk = (N + T - 1) / T;
    const int a = t * chunk;
    const int b = min(N, a + chunk);
    int cur = -1;
    float c = 0.0f;
    for (int n = a; n < b; ++n) {
        int gi = batch[n];
        if (gi != cur) {
            if (cur >= 0) atomicAdd(&counts[cur], c);
            cur = gi;
            c = 0.0f;
        }
        c += 1.0f;
    }
    if (cur >= 0) atomicAdd(&counts[cur], c);
}

// ---------------------------------------------------------------------------
// Head
// ---------------------------------------------------------------------------
__global__ __launch_bounds__(128) void head1_kernel(
    const float* __restrict__ gsum0, const float* __restrict__ gsum1,
    const float* __restrict__ counts,
    const float* __restrict__ Wh0, const float* __restrict__ bh0,
    float* __restrict__ t0, float* __restrict__ hstat0)
{
    const int gr = blockIdx.x;
    const int o = threadIdx.x;
    __shared__ float feat[256];
    float cnt = fmaxf(counts[gr], 1.0f);
    float inv = __fdividef(1.0f, cnt);
    if (o < 64) {
        float s = gsum0[gr * 64 + o];
        feat[o] = s * inv;
        feat[128 + o] = s;
    } else {
        int c = o - 64;
        float s = gsum1[gr * 64 + c];
        feat[64 + c] = s * inv;
        feat[192 + c] = s;
    }
    __syncthreads();
    float acc = bh0[o];
    for (int j = 0; j < 256; ++j) acc = fmaf(feat[j], Wh0[j * 128 + o], acc);
    float y = sigmoidf_(acc);
    t0[gr * 128 + o] = y;
    atomicAdd(&hstat0[o], y);
    atomicAdd(&hstat0[128 + o], y * y);
}

__global__ __launch_bounds__(64) void head2_kernel(
    const float* __restrict__ t0, const float* __restrict__ hstat0,
    const float* __restrict__ gh0, const float* __restrict__ beh0,
    const float* __restrict__ Wh1, const float* __restrict__ bh1,
    float* __restrict__ t1, float* __restrict__ hstat1)
{
    const int gr = blockIdx.x;
    const int o = threadIdx.x;
    __shared__ float bn0[128];
    const float invG = 1.0f / (float)N_GRAPHS;
    for (int j = o; j < 128; j += 64) {
        float m = hstat0[j] * invG;
        float v = hstat0[128 + j] * invG - m * m;
        bn0[j] = (t0[gr * 128 + j] - m) * rsqrtf(v + EPS) * gh0[j] + beh0[j];
    }
    __syncthreads();
    float acc = bh1[o];
    for (int j = 0; j < 128; ++j) acc = fmaf(bn0[j], Wh1[j * 64 + o], acc);
    float y = sigmoidf_(acc);
    t1[gr * 64 + o] = y;
    atomicAdd(&hstat1[o], y);
    atomicAdd(&hstat1[64 + o], y * y);
}

__global__ __launch_bounds__(64) void head3_kernel(
    const float* __restrict__ t1, const float* __restrict__ hstat1,
    const float* __restrict__ gh1, const float* __restrict__ beh1,
    const float* __restrict__ Wc, const float* __restrict__ bc,
    float* __restrict__ out)
{
    const int gr = blockIdx.x;
    const int o = threadIdx.x;
    const float invG = 1.0f / (float)N_GRAPHS;
    float m = hstat1[o] * invG;
    float v = hstat1[64 + o] * invG - m * m;
    float b = (t1[gr * 64 + o] - m) * rsqrtf(v + EPS) * gh1[o] + beh1[o];
    float p0 = b * Wc[o * 2];
    float p1 = b * Wc[o * 2 + 1];
#pragma unroll
    for (int off = 32; off > 0; off >>= 1) {
        p0 += __shfl_down(p0, off);
        p1 += __shfl_down(p1, off);
    }
    if (o == 0) {
        out[gr * 2] = p0 + bc[0];
        out[gr * 2 + 1] = p1 + bc[1];
    }
}

// ---------------------------------------------------------------------------
extern "C" void kernel_launch(void* const* d_in, const int* in_sizes, int n_in,
                              void* d_out, int out_size, void* d_ws, size_t ws_size,
                              hipStream_t stream)
{
    const float* x     = (const float*)d_in[0];
    const int*   ei    = (const int*)d_in[1];
    const int*   batch = (const int*)d_in[2];
    const int N = in_sizes[2];
    const int E = in_sizes[1] / 2;
    const int NCHUNK = (N + 1023) / 1024;

    const float *Wk0 = (const float*)d_in[3],  *bk0 = (const float*)d_in[4];
    const float *Wq0 = (const float*)d_in[5],  *bq0 = (const float*)d_in[6];
    const float *Wv0 = (const float*)d_in[7],  *bv0 = (const float*)d_in[8];
    const float *Ws0 = (const float*)d_in[9],  *cb0 = (const float*)d_in[10];
    const float *g0  = (const float*)d_in[11], *be0 = (const float*)d_in[12];
    const float *Wk1 = (const float*)d_in[13], *bk1 = (const float*)d_in[14];
    const float *Wq1 = (const float*)d_in[15], *bq1 = (const float*)d_in[16];
    const float *Wv1 = (const float*)d_in[17], *bv1 = (const float*)d_in[18];
    const float *Ws1 = (const float*)d_in[19], *cb1 = (const float*)d_in[20];
    const float *g1  = (const float*)d_in[21], *be1 = (const float*)d_in[22];
    const float *Wh0 = (const float*)d_in[23], *bh0 = (const float*)d_in[24];
    const float *gh0 = (const float*)d_in[25], *beh0 = (const float*)d_in[26];
    const float *Wh1 = (const float*)d_in[27], *bh1 = (const float*)d_in[28];
    const float *gh1 = (const float*)d_in[29], *beh1 = (const float*)d_in[30];
    const float *Wc  = (const float*)d_in[31], *bc  = (const float*)d_in[32];

    float*    ws = (float*)d_ws;
    float*    Y2 = ws;                          // N*128 fp32 [k|s]
    unsigned* QV = (unsigned*)(Y2 + (size_t)N * 128);  // N*64 packed fp16 q|v
    float*    H  = (float*)(QV + (size_t)N * 64);      // N*64 fp32
    int*   col     = (int*)(H + (size_t)N * 64);       // E
    int*   rowptr  = col + E;             // N+1
    int*   rp1loc  = rowptr + N + 1;      // N
    int*   cursor  = rp1loc + N;          // N
    int*   psum    = cursor + N;          // 256
    float* Wf0  = (float*)(psum + 256);   // 128*256
    float* bf0  = Wf0 + 128 * 256;        // 256
    float* Wf1  = bf0 + 256;              // 64*256
    float* bf1  = Wf1 + 64 * 256;         // 256
    float* Aaff = bf1 + 256;              // 64
    float* Baff = Aaff + 64;              // 64
    int*   deg     = (int*)(Baff + 64);   // N    <-- zero zone starts here
    float* gsum0  = (float*)(deg + N);    // 128*64
    float* gsum1  = gsum0 + 128 * 64;     // 128*64
    float* counts = gsum1 + 128 * 64;     // 128
    float* stats0 = counts + 128;         // 128
    float* stats1 = stats0 + 128;         // 128
    float* hstat0 = stats1 + 128;         // 256
    float* hstat1 = hstat0 + 256;         // 128
    size_t zbytes = (size_t)N * sizeof(int) +
                    (size_t)(128 * 64 * 2 + 128 * 3 + 256 + 128) * sizeof(float);
    float* t0 = hstat1 + 128;             // 128*128
    float* t1 = t0 + 128 * 128;           // 128*64

    hipMemsetAsync(deg, 0, zbytes, stream);

    // ---- CSR build + weight fusion (once) ----
    deg_kernel<<<256, 256, 0, stream>>>(ei, deg, E);
    scan1_kernel<<<NCHUNK, 256, 0, stream>>>(deg, rp1loc, psum, N);
    scan2_kernel<<<1, 256, 0, stream>>>(psum, NCHUNK);
    scan3_kernel<<<256, 256, 0, stream>>>(rp1loc, psum, rowptr, cursor, N);
    scatter_kernel<<<512, 256, 0, stream>>>(ei, cursor, col, E);
    fuse_w_kernel<<<64, 256, 0, stream>>>(Wk0, bk0, Wq0, bq0, Wv0, bv0, Ws0, cb0,
                                          Wf0, bf0, 128);
    fuse_w_kernel<<<64, 256, 0, stream>>>(Wk1, bk1, Wq1, bq1, Wv1, bv1, Ws1, cb1,
                                          Wf1, bf1, 64);
    counts_kernel<<<16, 256, 0, stream>>>(batch, counts, N);

    const float invN = 1.0f / (float)N;
    const int projBlocks = ((N + 63) / 64) * 2;

    // ---- layer 0 ----
    proj_kernel<128, false><<<projBlocks, 256, 0, stream>>>(
        x, Wf0, bf0, nullptr, nullptr, Y2, QV, N);
    agg_kernel<<<2048, 256, 0, stream>>>(rowptr, col, Y2, QV, H, stats0, N);
    prep_affine_kernel<<<1, 64, 0, stream>>>(stats0, g0, be0, Aaff, Baff, invN);
    readout_kernel<<<1024, 256, 0, stream>>>(H, stats0, g0, be0, batch, gsum0,
                                             N, invN);

    // ---- layer 1 (BN affine applied while staging H) ----
    proj_kernel<64, true><<<projBlocks, 256, 0, stream>>>(
        H, Wf1, bf1, Aaff, Baff, Y2, QV, N);
    agg_kernel<<<2048, 256, 0, stream>>>(rowptr, col, Y2, QV, H, stats1, N);
    readout_kernel<<<1024, 256, 0, stream>>>(H, stats1, g1, be1, batch, gsum1,
                                             N, invN);

    // ---- head ----
    head1_kernel<<<128, 128, 0, stream>>>(gsum0, gsum1, counts, Wh0, bh0, t0, hstat0);
    head2_kernel<<<128, 64, 0, stream>>>(t0, hstat0, gh0, beh0, Wh1, bh1, t1, hstat1);
    head3_kernel<<<128, 64, 0, stream>>>(t1, hstat1, gh1, beh1, Wc, bc, (float*)d_out);
}

// Round 7
// 664.266 us; speedup vs baseline: 1.9836x; 1.0488x over previous
//
#include <hip/hip_runtime.h>
#include <hip/hip_fp16.h>
#include <math.h>

#define EPS 1e-5f
#define N_GRAPHS 128

__device__ __forceinline__ float sigmoidf_(float x) {
    return __fdividef(1.0f, 1.0f + __expf(-x));
}

// ---------------------------------------------------------------------------
// Weight fusion with column permutation. Fused col c:
//   [0,64)=Wk, [64,128)=Ws, [128,256)= interleaved (q,v) pairs.
// ---------------------------------------------------------------------------
__global__ __launch_bounds__(256) void fuse_w_kernel(
    const float* __restrict__ Wk, const float* __restrict__ bk,
    const float* __restrict__ Wq, const float* __restrict__ bq,
    const float* __restrict__ Wv, const float* __restrict__ bv,
    const float* __restrict__ Ws, const float* __restrict__ cbv,
    float* __restrict__ Wf, float* __restrict__ bf, int K)
{
    int t = blockIdx.x * 256 + threadIdx.x;
    int total = K * 256;
    for (int i = t; i < total; i += gridDim.x * 256) {
        int k = i >> 8, c = i & 255;
        const float* W;
        int cc;
        if (c < 64)       { W = Wk; cc = c; }
        else if (c < 128) { W = Ws; cc = c - 64; }
        else { int j = c - 128; cc = j >> 1; W = (j & 1) ? Wv : Wq; }
        Wf[i] = W[k * 64 + cc];
    }
    if (t < 256) {
        int c = t;
        const float* b;
        int cc;
        if (c < 64)       { b = bk;  cc = c; }
        else if (c < 128) { b = cbv; cc = c - 64; }
        else { int j = c - 128; cc = j >> 1; b = (j & 1) ? bv : bq; }
        bf[t] = b[cc];
    }
}

// ---------------------------------------------------------------------------
// BN affine precompute for the layer-1 proj input: v = h*A + B.
// ---------------------------------------------------------------------------
__global__ __launch_bounds__(64) void prep_affine_kernel(
    const float* __restrict__ stats, const float* __restrict__ g,
    const float* __restrict__ be, float* __restrict__ Aaff,
    float* __restrict__ Baff, float invN)
{
    int c = threadIdx.x;
    float m = stats[c] * invN;
    float var = stats[64 + c] * invN - m * m;
    float rs = rsqrtf(var + EPS) * g[c];
    Aaff[c] = rs;
    Baff[c] = be[c] - m * rs;
}

// ---------------------------------------------------------------------------
// Projection: LDS-tiled fp32 GEMM, fused cols. Tile M=64 x N=128 (blockIdx&1).
// nb=0 -> fp32 [k|s] to Y2[N][128]; nb=1 -> fp16-packed (q,v) to QV[N][64].
// AFF: apply BN affine (per input column) while staging X.
// ---------------------------------------------------------------------------
template <int K, bool AFF>
__global__ __launch_bounds__(256) void proj_kernel(
    const float* __restrict__ X, const float* __restrict__ Wf,
    const float* __restrict__ bf,
    const float* __restrict__ Aaff, const float* __restrict__ Baff,
    float* __restrict__ Y2, unsigned* __restrict__ QV, int N)
{
    __shared__ __attribute__((aligned(16))) float As[16][72];
    __shared__ __attribute__((aligned(16))) float Bs[16][128];
    const int tid = threadIdx.x;
    const int nb = blockIdx.x & 1;
    const int n0 = (blockIdx.x >> 1) * 64;
    const int cg = tid & 31;
    const int mg = tid >> 5;
    const int ar = tid >> 2, akq = (tid & 3) * 4;
    const int bk_ = tid >> 4, bcol = (tid & 15) * 8;

    float acc[8][4];
#pragma unroll
    for (int r = 0; r < 8; ++r)
#pragma unroll
        for (int j = 0; j < 4; ++j) acc[r][j] = 0.0f;

    for (int k0 = 0; k0 < K; k0 += 16) {
        float4 av4 = make_float4(0.f, 0.f, 0.f, 0.f);
        int row = n0 + ar;
        if (row < N) av4 = *(const float4*)&X[(size_t)row * K + k0 + akq];
        if constexpr (AFF) {
            float4 Aa = *(const float4*)&Aaff[k0 + akq];
            float4 Bb = *(const float4*)&Baff[k0 + akq];
            av4.x = fmaf(av4.x, Aa.x, Bb.x);
            av4.y = fmaf(av4.y, Aa.y, Bb.y);
            av4.z = fmaf(av4.z, Aa.z, Bb.z);
            av4.w = fmaf(av4.w, Aa.w, Bb.w);
        }
        const float4 b0 = *(const float4*)&Wf[(size_t)(k0 + bk_) * 256 + nb * 128 + bcol];
        const float4 b1 = *(const float4*)&Wf[(size_t)(k0 + bk_) * 256 + nb * 128 + bcol + 4];
        __syncthreads();
        As[akq + 0][ar] = av4.x;
        As[akq + 1][ar] = av4.y;
        As[akq + 2][ar] = av4.z;
        As[akq + 3][ar] = av4.w;
        *(float4*)&Bs[bk_][bcol] = b0;
        *(float4*)&Bs[bk_][bcol + 4] = b1;
        __syncthreads();
#pragma unroll
        for (int kk = 0; kk < 16; ++kk) {
            float4 a0 = *(const float4*)&As[kk][8 * mg];
            float4 a1 = *(const float4*)&As[kk][8 * mg + 4];
            float4 bv = *(const float4*)&Bs[kk][4 * cg];
            float am[8] = {a0.x, a0.y, a0.z, a0.w, a1.x, a1.y, a1.z, a1.w};
#pragma unroll
            for (int r = 0; r < 8; ++r) {
                acc[r][0] = fmaf(am[r], bv.x, acc[r][0]);
                acc[r][1] = fmaf(am[r], bv.y, acc[r][1]);
                acc[r][2] = fmaf(am[r], bv.z, acc[r][2]);
                acc[r][3] = fmaf(am[r], bv.w, acc[r][3]);
            }
        }
    }

    float4 bias;
    bias.x = bf[nb * 128 + 4 * cg + 0];
    bias.y = bf[nb * 128 + 4 * cg + 1];
    bias.z = bf[nb * 128 + 4 * cg + 2];
    bias.w = bf[nb * 128 + 4 * cg + 3];
    const int nn = min(64, N - n0);
    if (nb == 0) {
#pragma unroll
        for (int r = 0; r < 8; ++r) {
            int row = 8 * mg + r;
            if (row < nn) {
                float4 o;
                o.x = acc[r][0] + bias.x;
                o.y = acc[r][1] + bias.y;
                o.z = acc[r][2] + bias.z;
                o.w = acc[r][3] + bias.w;
                *(float4*)&Y2[(size_t)(n0 + row) * 128 + 4 * cg] = o;
            }
        }
    } else {
#pragma unroll
        for (int r = 0; r < 8; ++r) {
            int row = 8 * mg + r;
            if (row < nn) {
                __half2 p0 = __floats2half2_rn(acc[r][0] + bias.x, acc[r][1] + bias.y);
                __half2 p1 = __floats2half2_rn(acc[r][2] + bias.z, acc[r][3] + bias.w);
                uint2 u;
                u.x = *reinterpret_cast<unsigned*>(&p0);
                u.y = *reinterpret_cast<unsigned*>(&p1);
                *(uint2*)&QV[(size_t)(n0 + row) * 64 + 2 * cg] = u;
            }
        }
    }
}

// ---------------------------------------------------------------------------
// CSR build: degree histogram -> 2-level exclusive scan -> scatter.
// ---------------------------------------------------------------------------
__global__ __launch_bounds__(256) void deg_kernel(
    const int* __restrict__ ei, int* __restrict__ deg, int E)
{
    int t = blockIdx.x * 256 + threadIdx.x;
    int T = gridDim.x * 256;
    for (int e = t; e < E; e += T) atomicAdd(&deg[ei[E + e]], 1);
}

__global__ __launch_bounds__(256) void scan1_kernel(
    const int* __restrict__ deg, int* __restrict__ rp1loc,
    int* __restrict__ psum, int N)
{
    __shared__ int s[256];
    const int b = blockIdx.x;
    const int base = b * 1024;
    const int t = threadIdx.x;
    int v[4], sum = 0;
#pragma unroll
    for (int i = 0; i < 4; ++i) {
        int idx = base + t * 4 + i;
        v[i] = (idx < N) ? deg[idx] : 0;
        sum += v[i];
    }
    s[t] = sum;
    __syncthreads();
    for (int off = 1; off < 256; off <<= 1) {
        int x = (t >= off) ? s[t - off] : 0;
        __syncthreads();
        s[t] += x;
        __syncthreads();
    }
    int run = s[t] - sum;
#pragma unroll
    for (int i = 0; i < 4; ++i) {
        run += v[i];
        int idx = base + t * 4 + i;
        if (idx < N) rp1loc[idx] = run;
    }
    if (t == 255) psum[b] = s[255];
}

__global__ __launch_bounds__(256) void scan2_kernel(int* __restrict__ psum, int NBLK)
{
    __shared__ int s[256];
    int t = threadIdx.x;
    int c = (t < NBLK) ? psum[t] : 0;
    s[t] = c;
    __syncthreads();
    for (int off = 1; off < 256; off <<= 1) {
        int x = (t >= off) ? s[t - off] : 0;
        __syncthreads();
        s[t] += x;
        __syncthreads();
    }
    if (t < NBLK) psum[t] = s[t] - c;
}

__global__ __launch_bounds__(256) void scan3_kernel(
    const int* __restrict__ rp1loc, const int* __restrict__ psum,
    int* __restrict__ rowptr, int* __restrict__ cursor, int N)
{
    int t = blockIdx.x * 256 + threadIdx.x;
    int T = gridDim.x * 256;
    for (int i = t; i < N; i += T) {
        rowptr[i + 1] = rp1loc[i] + psum[i >> 10];
        cursor[i] = (i == 0) ? 0 : rp1loc[i - 1] + psum[(i - 1) >> 10];
    }
    if (t == 0) rowptr[0] = 0;
}

__global__ __launch_bounds__(256) void scatter_kernel(
    const int* __restrict__ ei, int* __restrict__ cursor,
    int* __restrict__ col, int E)
{
    int t = blockIdx.x * 256 + threadIdx.x;
    int T = gridDim.x * 256;
    for (int e = t; e < E; e += T) {
        int d = ei[E + e];
        int pos = atomicAdd(&cursor[d], 1);
        col[pos] = ei[e];
    }
}

// ---------------------------------------------------------------------------
// Aggregation v5: contiguous node chunk per wave (uniform n -> scalar rowptr/
// batch loads). Per-edge gather = one dword from QV via (s<<6)|lane. Fuses
// sigmoid + BN channel stats + per-graph raw-y sums (run-length + atomics).
// ---------------------------------------------------------------------------
__global__ __launch_bounds__(256) void agg_kernel(
    const int* __restrict__ rowptr, const int* __restrict__ col,
    const float* __restrict__ Y2, const unsigned* __restrict__ QV,
    const int* __restrict__ batch,
    float* __restrict__ H, float* __restrict__ stats,
    float* __restrict__ gsumy, int N)
{
    const int tid = threadIdx.x;
    const int lane = tid & 63;
    const int wid = __builtin_amdgcn_readfirstlane(
        (int)((blockIdx.x * blockDim.x + tid) >> 6));
    const int NW = (gridDim.x * blockDim.x) >> 6;
    const int chunk = (N + NW - 1) / NW;
    const int nA = wid * chunk;
    const int nB = min(N, nA + chunk);

    float st1 = 0.0f, st2 = 0.0f;
    float gacc = 0.0f;
    int cur = -1;
    for (int n = nA; n < nB; ++n) {
        const int r0 = __builtin_amdgcn_readfirstlane(rowptr[n]);
        const int r1 = __builtin_amdgcn_readfirstlane(rowptr[n + 1]);
        float kk = Y2[(size_t)n * 128 + lane];
        float acc = Y2[(size_t)n * 128 + 64 + lane];
        int e = r0;
        while (e < r1) {
            int cnt = min(64, r1 - e);
            int my = (lane < cnt) ? col[e + lane] : 0;
            int j = 0;
            for (; j + 4 <= cnt; j += 4) {
                int s0 = __shfl(my, j);
                int s1 = __shfl(my, j + 1);
                int s2 = __shfl(my, j + 2);
                int s3 = __shfl(my, j + 3);
                unsigned u0 = QV[(((unsigned)s0) << 6) | lane];
                unsigned u1 = QV[(((unsigned)s1) << 6) | lane];
                unsigned u2 = QV[(((unsigned)s2) << 6) | lane];
                unsigned u3 = QV[(((unsigned)s3) << 6) | lane];
                float2 f0 = __half22float2(*reinterpret_cast<__half2*>(&u0));
                float2 f1 = __half22float2(*reinterpret_cast<__half2*>(&u1));
                float2 f2 = __half22float2(*reinterpret_cast<__half2*>(&u2));
                float2 f3 = __half22float2(*reinterpret_cast<__half2*>(&u3));
                acc += sigmoidf_(kk + f0.x) * f0.y;
                acc += sigmoidf_(kk + f1.x) * f1.y;
                acc += sigmoidf_(kk + f2.x) * f2.y;
                acc += sigmoidf_(kk + f3.x) * f3.y;
            }
            for (; j < cnt; ++j) {
                int s0 = __shfl(my, j);
                unsigned u0 = QV[(((unsigned)s0) << 6) | lane];
                float2 f0 = __half22float2(*reinterpret_cast<__half2*>(&u0));
                acc += sigmoidf_(kk + f0.x) * f0.y;
            }
            e += cnt;
        }
        float y = sigmoidf_(acc);
        H[(size_t)n * 64 + lane] = y;
        st1 += y;
        st2 += y * y;
        int gi = __builtin_amdgcn_readfirstlane(batch[n]);
        if (gi != cur) {
            if (cur >= 0) atomicAdd(&gsumy[cur * 64 + lane], gacc);
            gacc = 0.0f;
            cur = gi;
        }
        gacc += y;
    }
    if (cur >= 0) atomicAdd(&gsumy[cur * 64 + lane], gacc);

    __shared__ float red1[4][64], red2[4][64];
    const int w = tid >> 6;
    red1[w][lane] = st1;
    red2[w][lane] = st2;
    __syncthreads();
    if (tid < 64) {
        float a = red1[0][lane] + red1[1][lane] + red1[2][lane] + red1[3][lane];
        float c = red2[0][lane] + red2[1][lane] + red2[2][lane] + red2[3][lane];
        atomicAdd(&stats[lane], a);
        atomicAdd(&stats[64 + lane], c);
    }
}

__global__ __launch_bounds__(256) void counts_kernel(
    const int* __restrict__ batch, float* __restrict__ counts, int N)
{
    const int t = blockIdx.x * blockDim.x + threadIdx.x;
    const int T = gridDim.x * blockDim.x;
    const int chunk = (N + T - 1) / T;
    const int a = t * chunk;
    const int b = min(N, a + chunk);
    int cur = -1;
    float c = 0.0f;
    for (int n = a; n < b; ++n) {
        int gi = batch[n];
        if (gi != cur) {
            if (cur >= 0) atomicAdd(&counts[cur], c);
            cur = gi;
            c = 0.0f;
        }
        c += 1.0f;
    }
    if (cur >= 0) atomicAdd(&counts[cur], c);
}

// ---------------------------------------------------------------------------
// Head 1: reconstruct BN'd per-graph sums from raw-y sums via the affine
//   sum_v = rs*sum_y + cnt*(be - m*rs),  mean = sum_v / max(cnt,1)
// then t0 = sigmoid(feat @ Wh0 + bh0) + BN stats over graphs.
// ---------------------------------------------------------------------------
__global__ __launch_bounds__(128) void head1_kernel(
    const float* __restrict__ gsumy0, const float* __restrict__ gsumy1,
    const float* __restrict__ counts,
    const float* __restrict__ stats0, const float* __restrict__ stats1,
    const float* __restrict__ g0, const float* __restrict__ be0,
    const float* __restrict__ g1, const float* __restrict__ be1,
    const float* __restrict__ Wh0, const float* __restrict__ bh0,
    float* __restrict__ t0, float* __restrict__ hstat0, float invN)
{
    const int gr = blockIdx.x;
    const int o = threadIdx.x;   // 128: o<64 -> layer0 ch o; else layer1 ch o-64
    __shared__ float feat[256];

    const float* st = (o < 64) ? stats0 : stats1;
    const float* gg = (o < 64) ? g0 : g1;
    const float* bb = (o < 64) ? be0 : be1;
    const float* gs = (o < 64) ? gsumy0 : gsumy1;
    int c = o & 63;
    float m = st[c] * invN;
    float var = st[64 + c] * invN - m * m;
    float rs = rsqrtf(var + EPS) * gg[c];
    float off = bb[c] - m * rs;
    float cnt = counts[gr];
    float sv = rs * gs[gr * 64 + c] + cnt * off;
    float inv = __fdividef(1.0f, fmaxf(cnt, 1.0f));
    feat[o] = sv * inv;       // means: [0:64)=L0, [64:128)=L1
    feat[128 + o] = sv;       // sums:  [128:192)=L0, [192:256)=L1
    __syncthreads();

    float acc = bh0[o];
    for (int j = 0; j < 256; ++j) acc = fmaf(feat[j], Wh0[j * 128 + o], acc);
    float y = sigmoidf_(acc);
    t0[gr * 128 + o] = y;
    atomicAdd(&hstat0[o], y);
    atomicAdd(&hstat0[128 + o], y * y);
}

__global__ __launch_bounds__(64) void head2_kernel(
    const float* __restrict__ t0, const float* __restrict__ hstat0,
    const float* __restrict__ gh0, const float* __restrict__ beh0,
    const float* __restrict__ Wh1, const float* __restrict__ bh1,
    float* __restrict__ t1, float* __restrict__ hstat1)
{
    const int gr = blockIdx.x;
    const int o = threadIdx.x;
    __shared__ float bn0[128];
    const float invG = 1.0f / (float)N_GRAPHS;
    for (int j = o; j < 128; j += 64) {
        float m = hstat0[j] * invG;
        float v = hstat0[128 + j] * invG - m * m;
        bn0[j] = (t0[gr * 128 + j] - m) * rsqrtf(v + EPS) * gh0[j] + beh0[j];
    }
    __syncthreads();
    float acc = bh1[o];
    for (int j = 0; j < 128; ++j) acc = fmaf(bn0[j], Wh1[j * 64 + o], acc);
    float y = sigmoidf_(acc);
    t1[gr * 64 + o] = y;
    atomicAdd(&hstat1[o], y);
    atomicAdd(&hstat1[64 + o], y * y);
}

__global__ __launch_bounds__(64) void head3_kernel(
    const float* __restrict__ t1, const float* __restrict__ hstat1,
    const float* __restrict__ gh1, const float* __restrict__ beh1,
    const float* __restrict__ Wc, const float* __restrict__ bc,
    float* __restrict__ out)
{
    const int gr = blockIdx.x;
    const int o = threadIdx.x;
    const float invG = 1.0f / (float)N_GRAPHS;
    float m = hstat1[o] * invG;
    float v = hstat1[64 + o] * invG - m * m;
    float b = (t1[gr * 64 + o] - m) * rsqrtf(v + EPS) * gh1[o] + beh1[o];
    float p0 = b * Wc[o * 2];
    float p1 = b * Wc[o * 2 + 1];
#pragma unroll
    for (int off = 32; off > 0; off >>= 1) {
        p0 += __shfl_down(p0, off);
        p1 += __shfl_down(p1, off);
    }
    if (o == 0) {
        out[gr * 2] = p0 + bc[0];
        out[gr * 2 + 1] = p1 + bc[1];
    }
}

// ---------------------------------------------------------------------------
extern "C" void kernel_launch(void* const* d_in, const int* in_sizes, int n_in,
                              void* d_out, int out_size, void* d_ws, size_t ws_size,
                              hipStream_t stream)
{
    const float* x     = (const float*)d_in[0];
    const int*   ei    = (const int*)d_in[1];
    const int*   batch = (const int*)d_in[2];
    const int N = in_sizes[2];
    const int E = in_sizes[1] / 2;
    const int NCHUNK = (N + 1023) / 1024;

    const float *Wk0 = (const float*)d_in[3],  *bk0 = (const float*)d_in[4];
    const float *Wq0 = (const float*)d_in[5],  *bq0 = (const float*)d_in[6];
    const float *Wv0 = (const float*)d_in[7],  *bv0 = (const float*)d_in[8];
    const float *Ws0 = (const float*)d_in[9],  *cb0 = (const float*)d_in[10];
    const float *g0  = (const float*)d_in[11], *be0 = (const float*)d_in[12];
    const float *Wk1 = (const float*)d_in[13], *bk1 = (const float*)d_in[14];
    const float *Wq1 = (const float*)d_in[15], *bq1 = (const float*)d_in[16];
    const float *Wv1 = (const float*)d_in[17], *bv1 = (const float*)d_in[18];
    const float *Ws1 = (const float*)d_in[19], *cb1 = (const float*)d_in[20];
    const float *g1  = (const float*)d_in[21], *be1 = (const float*)d_in[22];
    const float *Wh0 = (const float*)d_in[23], *bh0 = (const float*)d_in[24];
    const float *gh0 = (const float*)d_in[25], *beh0 = (const float*)d_in[26];
    const float *Wh1 = (const float*)d_in[27], *bh1 = (const float*)d_in[28];
    const float *gh1 = (const float*)d_in[29], *beh1 = (const float*)d_in[30];
    const float *Wc  = (const float*)d_in[31], *bc  = (const float*)d_in[32];

    float*    ws = (float*)d_ws;
    float*    Y2 = ws;                          // N*128 fp32 [k|s]
    unsigned* QV = (unsigned*)(Y2 + (size_t)N * 128);  // N*64 packed fp16 q|v
    float*    H  = (float*)(QV + (size_t)N * 64);      // N*64 fp32 (raw y)
    int*   col     = (int*)(H + (size_t)N * 64);       // E
    int*   rowptr  = col + E;             // N+1
    int*   rp1loc  = rowptr + N + 1;      // N
    int*   cursor  = rp1loc + N;          // N
    int*   psum    = cursor + N;          // 256
    float* Wf0  = (float*)(psum + 256);   // 128*256
    float* bf0  = Wf0 + 128 * 256;        // 256
    float* Wf1  = bf0 + 256;              // 64*256
    float* bf1  = Wf1 + 64 * 256;         // 256
    float* Aaff = bf1 + 256;              // 64
    float* Baff = Aaff + 64;              // 64
    int*   deg     = (int*)(Baff + 64);   // N    <-- zero zone starts here
    float* gsumy0 = (float*)(deg + N);    // 128*64
    float* gsumy1 = gsumy0 + 128 * 64;    // 128*64
    float* counts = gsumy1 + 128 * 64;    // 128
    float* stats0 = counts + 128;         // 128
    float* stats1 = stats0 + 128;         // 128
    float* hstat0 = stats1 + 128;         // 256
    float* hstat1 = hstat0 + 256;         // 128
    size_t zbytes = (size_t)N * sizeof(int) +
                    (size_t)(128 * 64 * 2 + 128 * 3 + 256 + 128) * sizeof(float);
    float* t0 = hstat1 + 128;             // 128*128
    float* t1 = t0 + 128 * 128;           // 128*64

    hipMemsetAsync(deg, 0, zbytes, stream);

    // ---- CSR build + weight fusion (once) ----
    deg_kernel<<<256, 256, 0, stream>>>(ei, deg, E);
    scan1_kernel<<<NCHUNK, 256, 0, stream>>>(deg, rp1loc, psum, N);
    scan2_kernel<<<1, 256, 0, stream>>>(psum, NCHUNK);
    scan3_kernel<<<256, 256, 0, stream>>>(rp1loc, psum, rowptr, cursor, N);
    scatter_kernel<<<512, 256, 0, stream>>>(ei, cursor, col, E);
    fuse_w_kernel<<<64, 256, 0, stream>>>(Wk0, bk0, Wq0, bq0, Wv0, bv0, Ws0, cb0,
                                          Wf0, bf0, 128);
    fuse_w_kernel<<<64, 256, 0, stream>>>(Wk1, bk1, Wq1, bq1, Wv1, bv1, Ws1, cb1,
                                          Wf1, bf1, 64);
    counts_kernel<<<16, 256, 0, stream>>>(batch, counts, N);

    const float invN = 1.0f / (float)N;
    const int projBlocks = ((N + 63) / 64) * 2;

    // ---- layer 0 ----
    proj_kernel<128, false><<<projBlocks, 256, 0, stream>>>(
        x, Wf0, bf0, nullptr, nullptr, Y2, QV, N);
    agg_kernel<<<2048, 256, 0, stream>>>(rowptr, col, Y2, QV, batch,
                                         H, stats0, gsumy0, N);
    prep_affine_kernel<<<1, 64, 0, stream>>>(stats0, g0, be0, Aaff, Baff, invN);

    // ---- layer 1 (BN affine applied while staging H) ----
    proj_kernel<64, true><<<projBlocks, 256, 0, stream>>>(
        H, Wf1, bf1, Aaff, Baff, Y2, QV, N);
    agg_kernel<<<2048, 256, 0, stream>>>(rowptr, col, Y2, QV, batch,
                                         H, stats1, gsumy1, N);

    // ---- head ----
    head1_kernel<<<128, 128, 0, stream>>>(gsumy0, gsumy1, counts,
                                          stats0, stats1, g0, be0, g1, be1,
                                          Wh0, bh0, t0, hstat0, invN);
    head2_kernel<<<128, 64, 0, stream>>>(t0, hstat0, gh0, beh0, Wh1, bh1, t1, hstat1);
    head3_kernel<<<128, 64, 0, stream>>>(t1, hstat1, gh1, beh1, Wc, bc, (float*)d_out);
}

// Round 8
// 649.809 us; speedup vs baseline: 2.0277x; 1.0222x over previous
//
#include <hip/hip_runtime.h>
#include <hip/hip_fp16.h>
#include <math.h>

#define EPS 1e-5f
#define N_GRAPHS 128

__device__ __forceinline__ float sigmoidf_(float x) {
    return __fdividef(1.0f, 1.0f + __expf(-x));
}

// ---------------------------------------------------------------------------
// Fused prep: block-range partition.
//  [0,256):  deg histogram      [256,320): fuse_w layer0 (K=128)
//  [320,384): fuse_w layer1 (K=64)        [384,400): per-graph counts
// ---------------------------------------------------------------------------
__device__ __forceinline__ void fuse_w_body(
    int b0, int blk, int tid,
    const float* __restrict__ Wk, const float* __restrict__ bk,
    const float* __restrict__ Wq, const float* __restrict__ bq,
    const float* __restrict__ Wv, const float* __restrict__ bv,
    const float* __restrict__ Ws, const float* __restrict__ cbv,
    float* __restrict__ Wf, float* __restrict__ bf, int K)
{
    int t = (blk - b0) * 256 + tid;
    int total = K * 256;
    for (int i = t; i < total; i += 64 * 256) {
        int k = i >> 8, c = i & 255;
        const float* W;
        int cc;
        if (c < 64)       { W = Wk; cc = c; }
        else if (c < 128) { W = Ws; cc = c - 64; }
        else { int j = c - 128; cc = j >> 1; W = (j & 1) ? Wv : Wq; }
        Wf[i] = W[k * 64 + cc];
    }
    if (t < 256) {
        int c = t;
        const float* b;
        int cc;
        if (c < 64)       { b = bk;  cc = c; }
        else if (c < 128) { b = cbv; cc = c - 64; }
        else { int j = c - 128; cc = j >> 1; b = (j & 1) ? bv : bq; }
        bf[t] = b[cc];
    }
}

__global__ __launch_bounds__(256) void prep_kernel(
    const int* __restrict__ ei, int* __restrict__ deg, int E,
    const int* __restrict__ batch, float* __restrict__ counts, int N,
    const float* __restrict__ Wk0, const float* __restrict__ bk0,
    const float* __restrict__ Wq0, const float* __restrict__ bq0,
    const float* __restrict__ Wv0, const float* __restrict__ bv0,
    const float* __restrict__ Ws0, const float* __restrict__ cb0,
    float* __restrict__ Wf0, float* __restrict__ bf0,
    const float* __restrict__ Wk1, const float* __restrict__ bk1,
    const float* __restrict__ Wq1, const float* __restrict__ bq1,
    const float* __restrict__ Wv1, const float* __restrict__ bv1,
    const float* __restrict__ Ws1, const float* __restrict__ cb1,
    float* __restrict__ Wf1, float* __restrict__ bf1)
{
    const int blk = blockIdx.x;
    const int tid = threadIdx.x;
    if (blk < 256) {
        int t = blk * 256 + tid;
        for (int e = t; e < E; e += 256 * 256) atomicAdd(&deg[ei[E + e]], 1);
    } else if (blk < 320) {
        fuse_w_body(256, blk, tid, Wk0, bk0, Wq0, bq0, Wv0, bv0, Ws0, cb0,
                    Wf0, bf0, 128);
    } else if (blk < 384) {
        fuse_w_body(320, blk, tid, Wk1, bk1, Wq1, bq1, Wv1, bv1, Ws1, cb1,
                    Wf1, bf1, 64);
    } else {
        const int t = (blk - 384) * 256 + tid;
        const int T = 16 * 256;
        const int chunk = (N + T - 1) / T;
        const int a = t * chunk;
        const int b = min(N, a + chunk);
        int cur = -1;
        float c = 0.0f;
        for (int n = a; n < b; ++n) {
            int gi = batch[n];
            if (gi != cur) {
                if (cur >= 0) atomicAdd(&counts[cur], c);
                cur = gi;
                c = 0.0f;
            }
            c += 1.0f;
        }
        if (cur >= 0) atomicAdd(&counts[cur], c);
    }
}

// ---------------------------------------------------------------------------
// BN affine precompute for the layer-1 proj input: v = h*A + B.
// ---------------------------------------------------------------------------
__global__ __launch_bounds__(64) void prep_affine_kernel(
    const float* __restrict__ stats, const float* __restrict__ g,
    const float* __restrict__ be, float* __restrict__ Aaff,
    float* __restrict__ Baff, float invN)
{
    int c = threadIdx.x;
    float m = stats[c] * invN;
    float var = stats[64 + c] * invN - m * m;
    float rs = rsqrtf(var + EPS) * g[c];
    Aaff[c] = rs;
    Baff[c] = be[c] - m * rs;
}

// ---------------------------------------------------------------------------
// Projection: LDS-tiled fp32 GEMM, fused cols. Tile M=64 x N=128 (blockIdx&1).
// nb=0 -> fp32 [k|s] to Y2[N][128]; nb=1 -> fp16-packed (q,v) to QV[N][64].
// AFF: apply BN affine (per input column) while staging X.
// ---------------------------------------------------------------------------
template <int K, bool AFF>
__global__ __launch_bounds__(256) void proj_kernel(
    const float* __restrict__ X, const float* __restrict__ Wf,
    const float* __restrict__ bf,
    const float* __restrict__ Aaff, const float* __restrict__ Baff,
    float* __restrict__ Y2, unsigned* __restrict__ QV, int N)
{
    __shared__ __attribute__((aligned(16))) float As[16][72];
    __shared__ __attribute__((aligned(16))) float Bs[16][128];
    const int tid = threadIdx.x;
    const int nb = blockIdx.x & 1;
    const int n0 = (blockIdx.x >> 1) * 64;
    const int cg = tid & 31;
    const int mg = tid >> 5;
    const int ar = tid >> 2, akq = (tid & 3) * 4;
    const int bk_ = tid >> 4, bcol = (tid & 15) * 8;

    float acc[8][4];
#pragma unroll
    for (int r = 0; r < 8; ++r)
#pragma unroll
        for (int j = 0; j < 4; ++j) acc[r][j] = 0.0f;

    for (int k0 = 0; k0 < K; k0 += 16) {
        float4 av4 = make_float4(0.f, 0.f, 0.f, 0.f);
        int row = n0 + ar;
        if (row < N) av4 = *(const float4*)&X[(size_t)row * K + k0 + akq];
        if constexpr (AFF) {
            float4 Aa = *(const float4*)&Aaff[k0 + akq];
            float4 Bb = *(const float4*)&Baff[k0 + akq];
            av4.x = fmaf(av4.x, Aa.x, Bb.x);
            av4.y = fmaf(av4.y, Aa.y, Bb.y);
            av4.z = fmaf(av4.z, Aa.z, Bb.z);
            av4.w = fmaf(av4.w, Aa.w, Bb.w);
        }
        const float4 b0 = *(const float4*)&Wf[(size_t)(k0 + bk_) * 256 + nb * 128 + bcol];
        const float4 b1 = *(const float4*)&Wf[(size_t)(k0 + bk_) * 256 + nb * 128 + bcol + 4];
        __syncthreads();
        As[akq + 0][ar] = av4.x;
        As[akq + 1][ar] = av4.y;
        As[akq + 2][ar] = av4.z;
        As[akq + 3][ar] = av4.w;
        *(float4*)&Bs[bk_][bcol] = b0;
        *(float4*)&Bs[bk_][bcol + 4] = b1;
        __syncthreads();
#pragma unroll
        for (int kk = 0; kk < 16; ++kk) {
            float4 a0 = *(const float4*)&As[kk][8 * mg];
            float4 a1 = *(const float4*)&As[kk][8 * mg + 4];
            float4 bv = *(const float4*)&Bs[kk][4 * cg];
            float am[8] = {a0.x, a0.y, a0.z, a0.w, a1.x, a1.y, a1.z, a1.w};
#pragma unroll
            for (int r = 0; r < 8; ++r) {
                acc[r][0] = fmaf(am[r], bv.x, acc[r][0]);
                acc[r][1] = fmaf(am[r], bv.y, acc[r][1]);
                acc[r][2] = fmaf(am[r], bv.z, acc[r][2]);
                acc[r][3] = fmaf(am[r], bv.w, acc[r][3]);
            }
        }
    }

    float4 bias;
    bias.x = bf[nb * 128 + 4 * cg + 0];
    bias.y = bf[nb * 128 + 4 * cg + 1];
    bias.z = bf[nb * 128 + 4 * cg + 2];
    bias.w = bf[nb * 128 + 4 * cg + 3];
    const int nn = min(64, N - n0);
    if (nb == 0) {
#pragma unroll
        for (int r = 0; r < 8; ++r) {
            int row = 8 * mg + r;
            if (row < nn) {
                float4 o;
                o.x = acc[r][0] + bias.x;
                o.y = acc[r][1] + bias.y;
                o.z = acc[r][2] + bias.z;
                o.w = acc[r][3] + bias.w;
                *(float4*)&Y2[(size_t)(n0 + row) * 128 + 4 * cg] = o;
            }
        }
    } else {
#pragma unroll
        for (int r = 0; r < 8; ++r) {
            int row = 8 * mg + r;
            if (row < nn) {
                __half2 p0 = __floats2half2_rn(acc[r][0] + bias.x, acc[r][1] + bias.y);
                __half2 p1 = __floats2half2_rn(acc[r][2] + bias.z, acc[r][3] + bias.w);
                uint2 u;
                u.x = *reinterpret_cast<unsigned*>(&p0);
                u.y = *reinterpret_cast<unsigned*>(&p1);
                *(uint2*)&QV[(size_t)(n0 + row) * 64 + 2 * cg] = u;
            }
        }
    }
}

// ---------------------------------------------------------------------------
// CSR scans + scatter.
// ---------------------------------------------------------------------------
__global__ __launch_bounds__(256) void scan1_kernel(
    const int* __restrict__ deg, int* __restrict__ rp1loc,
    int* __restrict__ psum, int N)
{
    __shared__ int s[256];
    const int b = blockIdx.x;
    const int base = b * 1024;
    const int t = threadIdx.x;
    int v[4], sum = 0;
#pragma unroll
    for (int i = 0; i < 4; ++i) {
        int idx = base + t * 4 + i;
        v[i] = (idx < N) ? deg[idx] : 0;
        sum += v[i];
    }
    s[t] = sum;
    __syncthreads();
    for (int off = 1; off < 256; off <<= 1) {
        int x = (t >= off) ? s[t - off] : 0;
        __syncthreads();
        s[t] += x;
        __syncthreads();
    }
    int run = s[t] - sum;
#pragma unroll
    for (int i = 0; i < 4; ++i) {
        run += v[i];
        int idx = base + t * 4 + i;
        if (idx < N) rp1loc[idx] = run;
    }
    if (t == 255) psum[b] = s[255];
}

__global__ __launch_bounds__(256) void scan2_kernel(int* __restrict__ psum, int NBLK)
{
    __shared__ int s[256];
    int t = threadIdx.x;
    int c = (t < NBLK) ? psum[t] : 0;
    s[t] = c;
    __syncthreads();
    for (int off = 1; off < 256; off <<= 1) {
        int x = (t >= off) ? s[t - off] : 0;
        __syncthreads();
        s[t] += x;
        __syncthreads();
    }
    if (t < NBLK) psum[t] = s[t] - c;
}

__global__ __launch_bounds__(256) void scan3_kernel(
    const int* __restrict__ rp1loc, const int* __restrict__ psum,
    int* __restrict__ rowptr, int* __restrict__ cursor, int N)
{
    int t = blockIdx.x * 256 + threadIdx.x;
    int T = gridDim.x * 256;
    for (int i = t; i < N; i += T) {
        rowptr[i + 1] = rp1loc[i] + psum[i >> 10];
        cursor[i] = (i == 0) ? 0 : rp1loc[i - 1] + psum[(i - 1) >> 10];
    }
    if (t == 0) rowptr[0] = 0;
}

__global__ __launch_bounds__(256) void scatter_kernel(
    const int* __restrict__ ei, int* __restrict__ cursor,
    int* __restrict__ col, int E)
{
    int t = blockIdx.x * 256 + threadIdx.x;
    int T = gridDim.x * 256;
    for (int e = t; e < E; e += T) {
        int d = ei[E + e];
        int pos = atomicAdd(&cursor[d], 1);
        col[pos] = ei[e];
    }
}

// ---------------------------------------------------------------------------
// Aggregation v6: contiguous node chunk per wave; col consumed through a
// sliding 64-edge double-buffered window crossing node boundaries (one col
// load per 64 edges, prefetched); next node's kk/preinit prefetched during
// the current node's edge loop. sigmoid via fused exp2.
// Fuses BN channel stats + per-graph raw-y sums.
// ---------------------------------------------------------------------------
__global__ __launch_bounds__(256) void agg_kernel(
    const int* __restrict__ rowptr, const int* __restrict__ col,
    const float* __restrict__ Y2, const unsigned* __restrict__ QV,
    const int* __restrict__ batch,
    float* __restrict__ H, float* __restrict__ stats,
    float* __restrict__ gsumy, int N)
{
    const int tid = threadIdx.x;
    const int lane = tid & 63;
    const int wid = __builtin_amdgcn_readfirstlane(
        (int)((blockIdx.x * blockDim.x + tid) >> 6));
    const int NW = (gridDim.x * blockDim.x) >> 6;
    const int chunk = (N + NW - 1) / NW;
    const int nA = wid * chunk;
    const int nB = min(N, nA + chunk);

    float st1 = 0.0f, st2 = 0.0f;
    float gacc = 0.0f;
    int cur = -1;

    if (nA < nB) {
        const float L2E = 1.44269504f;
        int w0 = __builtin_amdgcn_readfirstlane(rowptr[nA]);
        const int wend = __builtin_amdgcn_readfirstlane(rowptr[nB]);
        int wpos = 0;
        int my = (w0 + lane < wend) ? col[w0 + lane] : 0;
        int nxt = (w0 + 64 + lane < wend) ? col[w0 + 64 + lane] : 0;

        float kk = Y2[(size_t)nA * 128 + lane];
        float acc = Y2[(size_t)nA * 128 + 64 + lane];

        for (int n = nA; n < nB; ++n) {
            const int r1 = __builtin_amdgcn_readfirstlane(rowptr[n + 1]);
            // prefetch next node's k / preinit
            float kkn = 0.0f, accn = 0.0f;
            if (n + 1 < nB) {
                kkn = Y2[(size_t)(n + 1) * 128 + lane];
                accn = Y2[(size_t)(n + 1) * 128 + 64 + lane];
            }
            const float nkl = kk * (-L2E);
            int rem = r1 - (w0 + wpos);
            while (rem > 0) {
                int take = min(rem, 64 - wpos);
                int j = 0;
                for (; j + 4 <= take; j += 4) {
                    int s0 = __shfl(my, wpos + j);
                    int s1 = __shfl(my, wpos + j + 1);
                    int s2 = __shfl(my, wpos + j + 2);
                    int s3 = __shfl(my, wpos + j + 3);
                    unsigned u0 = QV[(((unsigned)s0) << 6) | lane];
                    unsigned u1 = QV[(((unsigned)s1) << 6) | lane];
                    unsigned u2 = QV[(((unsigned)s2) << 6) | lane];
                    unsigned u3 = QV[(((unsigned)s3) << 6) | lane];
                    float2 f0 = __half22float2(*reinterpret_cast<__half2*>(&u0));
                    float2 f1 = __half22float2(*reinterpret_cast<__half2*>(&u1));
                    float2 f2 = __half22float2(*reinterpret_cast<__half2*>(&u2));
                    float2 f3 = __half22float2(*reinterpret_cast<__half2*>(&u3));
                    float e0 = __builtin_amdgcn_exp2f(fmaf(f0.x, -L2E, nkl));
                    float e1 = __builtin_amdgcn_exp2f(fmaf(f1.x, -L2E, nkl));
                    float e2 = __builtin_amdgcn_exp2f(fmaf(f2.x, -L2E, nkl));
                    float e3 = __builtin_amdgcn_exp2f(fmaf(f3.x, -L2E, nkl));
                    acc = fmaf(__frcp_rn(1.0f + e0), f0.y, acc);
                    acc = fmaf(__frcp_rn(1.0f + e1), f1.y, acc);
                    acc = fmaf(__frcp_rn(1.0f + e2), f2.y, acc);
                    acc = fmaf(__frcp_rn(1.0f + e3), f3.y, acc);
                }
                for (; j < take; ++j) {
                    int s0 = __shfl(my, wpos + j);
                    unsigned u0 = QV[(((unsigned)s0) << 6) | lane];
                    float2 f0 = __half22float2(*reinterpret_cast<__half2*>(&u0));
                    float e0 = __builtin_amdgcn_exp2f(fmaf(f0.x, -L2E, nkl));
                    acc = fmaf(__frcp_rn(1.0f + e0), f0.y, acc);
                }
                wpos += take;
                rem -= take;
                if (wpos == 64) {
                    w0 += 64;
                    wpos = 0;
                    my = nxt;
                    nxt = (w0 + 64 + lane < wend) ? col[w0 + 64 + lane] : 0;
                }
            }
            float y = sigmoidf_(acc);
            H[(size_t)n * 64 + lane] = y;
            st1 += y;
            st2 += y * y;
            int gi = __builtin_amdgcn_readfirstlane(batch[n]);
            if (gi != cur) {
                if (cur >= 0) atomicAdd(&gsumy[cur * 64 + lane], gacc);
                gacc = 0.0f;
                cur = gi;
            }
            gacc += y;
            kk = kkn;
            acc = accn;
        }
        if (cur >= 0) atomicAdd(&gsumy[cur * 64 + lane], gacc);
    }

    __shared__ float red1[4][64], red2[4][64];
    const int w = tid >> 6;
    red1[w][lane] = st1;
    red2[w][lane] = st2;
    __syncthreads();
    if (tid < 64) {
        float a = red1[0][lane] + red1[1][lane] + red1[2][lane] + red1[3][lane];
        float c = red2[0][lane] + red2[1][lane] + red2[2][lane] + red2[3][lane];
        atomicAdd(&stats[lane], a);
        atomicAdd(&stats[64 + lane], c);
    }
}

// ---------------------------------------------------------------------------
// Head 1: reconstruct BN'd per-graph sums from raw-y sums via the affine
//   sum_v = rs*sum_y + cnt*(be - m*rs),  mean = sum_v / max(cnt,1)
// ---------------------------------------------------------------------------
__global__ __launch_bounds__(128) void head1_kernel(
    const float* __restrict__ gsumy0, const float* __restrict__ gsumy1,
    const float* __restrict__ counts,
    const float* __restrict__ stats0, const float* __restrict__ stats1,
    const float* __restrict__ g0, const float* __restrict__ be0,
    const float* __restrict__ g1, const float* __restrict__ be1,
    const float* __restrict__ Wh0, const float* __restrict__ bh0,
    float* __restrict__ t0, float* __restrict__ hstat0, float invN)
{
    const int gr = blockIdx.x;
    const int o = threadIdx.x;
    __shared__ float feat[256];

    const float* st = (o < 64) ? stats0 : stats1;
    const float* gg = (o < 64) ? g0 : g1;
    const float* bb = (o < 64) ? be0 : be1;
    const float* gs = (o < 64) ? gsumy0 : gsumy1;
    int c = o & 63;
    float m = st[c] * invN;
    float var = st[64 + c] * invN - m * m;
    float rs = rsqrtf(var + EPS) * gg[c];
    float off = bb[c] - m * rs;
    float cnt = counts[gr];
    float sv = rs * gs[gr * 64 + c] + cnt * off;
    float inv = __fdividef(1.0f, fmaxf(cnt, 1.0f));
    feat[o] = sv * inv;
    feat[128 + o] = sv;
    __syncthreads();

    float acc = bh0[o];
    for (int j = 0; j < 256; ++j) acc = fmaf(feat[j], Wh0[j * 128 + o], acc);
    float y = sigmoidf_(acc);
    t0[gr * 128 + o] = y;
    atomicAdd(&hstat0[o], y);
    atomicAdd(&hstat0[128 + o], y * y);
}

__global__ __launch_bounds__(64) void head2_kernel(
    const float* __restrict__ t0, const float* __restrict__ hstat0,
    const float* __restrict__ gh0, const float* __restrict__ beh0,
    const float* __restrict__ Wh1, const float* __restrict__ bh1,
    float* __restrict__ t1, float* __restrict__ hstat1)
{
    const int gr = blockIdx.x;
    const int o = threadIdx.x;
    __shared__ float bn0[128];
    const float invG = 1.0f / (float)N_GRAPHS;
    for (int j = o; j < 128; j += 64) {
        float m = hstat0[j] * invG;
        float v = hstat0[128 + j] * invG - m * m;
        bn0[j] = (t0[gr * 128 + j] - m) * rsqrtf(v + EPS) * gh0[j] + beh0[j];
    }
    __syncthreads();
    float acc = bh1[o];
    for (int j = 0; j < 128; ++j) acc = fmaf(bn0[j], Wh1[j * 64 + o], acc);
    float y = sigmoidf_(acc);
    t1[gr * 64 + o] = y;
    atomicAdd(&hstat1[o], y);
    atomicAdd(&hstat1[64 + o], y * y);
}

__global__ __launch_bounds__(64) void head3_kernel(
    const float* __restrict__ t1, const float* __restrict__ hstat1,
    const float* __restrict__ gh1, const float* __restrict__ beh1,
    const float* __restrict__ Wc, const float* __restrict__ bc,
    float* __restrict__ out)
{
    const int gr = blockIdx.x;
    const int o = threadIdx.x;
    const float invG = 1.0f / (float)N_GRAPHS;
    float m = hstat1[o] * invG;
    float v = hstat1[64 + o] * invG - m * m;
    float b = (t1[gr * 64 + o] - m) * rsqrtf(v + EPS) * gh1[o] + beh1[o];
    float p0 = b * Wc[o * 2];
    float p1 = b * Wc[o * 2 + 1];
#pragma unroll
    for (int off = 32; off > 0; off >>= 1) {
        p0 += __shfl_down(p0, off);
        p1 += __shfl_down(p1, off);
    }
    if (o == 0) {
        out[gr * 2] = p0 + bc[0];
        out[gr * 2 + 1] = p1 + bc[1];
    }
}

// ---------------------------------------------------------------------------
extern "C" void kernel_launch(void* const* d_in, const int* in_sizes, int n_in,
                              void* d_out, int out_size, void* d_ws, size_t ws_size,
                              hipStream_t stream)
{
    const float* x     = (const float*)d_in[0];
    const int*   ei    = (const int*)d_in[1];
    const int*   batch = (const int*)d_in[2];
    const int N = in_sizes[2];
    const int E = in_sizes[1] / 2;
    const int NCHUNK = (N + 1023) / 1024;

    const float *Wk0 = (const float*)d_in[3],  *bk0 = (const float*)d_in[4];
    const float *Wq0 = (const float*)d_in[5],  *bq0 = (const float*)d_in[6];
    const float *Wv0 = (const float*)d_in[7],  *bv0 = (const float*)d_in[8];
    const float *Ws0 = (const float*)d_in[9],  *cb0 = (const float*)d_in[10];
    const float *g0  = (const float*)d_in[11], *be0 = (const float*)d_in[12];
    const float *Wk1 = (const float*)d_in[13], *bk1 = (const float*)d_in[14];
    const float *Wq1 = (const float*)d_in[15], *bq1 = (const float*)d_in[16];
    const float *Wv1 = (const float*)d_in[17], *bv1 = (const float*)d_in[18];
    const float *Ws1 = (const float*)d_in[19], *cb1 = (const float*)d_in[20];
    const float *g1  = (const float*)d_in[21], *be1 = (const float*)d_in[22];
    const float *Wh0 = (const float*)d_in[23], *bh0 = (const float*)d_in[24];
    const float *gh0 = (const float*)d_in[25], *beh0 = (const float*)d_in[26];
    const float *Wh1 = (const float*)d_in[27], *bh1 = (const float*)d_in[28];
    const float *gh1 = (const float*)d_in[29], *beh1 = (const float*)d_in[30];
    const float *Wc  = (const float*)d_in[31], *bc  = (const float*)d_in[32];

    float*    ws = (float*)d_ws;
    float*    Y2 = ws;                          // N*128 fp32 [k|s]
    unsigned* QV = (unsigned*)(Y2 + (size_t)N * 128);  // N*64 packed fp16 q|v
    float*    H  = (float*)(QV + (size_t)N * 64);      // N*64 fp32 (raw y)
    int*   col     = (int*)(H + (size_t)N * 64);       // E
    int*   rowptr  = col + E;             // N+1
    int*   rp1loc  = rowptr + N + 1;      // N
    int*   cursor  = rp1loc + N;          // N
    int*   psum    = cursor + N;          // 256
    float* Wf0  = (float*)(psum + 256);   // 128*256
    float* bf0  = Wf0 + 128 * 256;        // 256
    float* Wf1  = bf0 + 256;              // 64*256
    float* bf1  = Wf1 + 64 * 256;         // 256
    float* Aaff = bf1 + 256;              // 64
    float* Baff = Aaff + 64;              // 64
    int*   deg     = (int*)(Baff + 64);   // N    <-- zero zone starts here
    float* gsumy0 = (float*)(deg + N);    // 128*64
    float* gsumy1 = gsumy0 + 128 * 64;    // 128*64
    float* counts = gsumy1 + 128 * 64;    // 128
    float* stats0 = counts + 128;         // 128
    float* stats1 = stats0 + 128;         // 128
    float* hstat0 = stats1 + 128;         // 256
    float* hstat1 = hstat0 + 256;         // 128
    size_t zbytes = (size_t)N * sizeof(int) +
                    (size_t)(128 * 64 * 2 + 128 * 3 + 256 + 128) * sizeof(float);
    float* t0 = hstat1 + 128;             // 128*128
    float* t1 = t0 + 128 * 128;           // 128*64

    hipMemsetAsync(deg, 0, zbytes, stream);

    // ---- fused prep (deg + counts + weight fusion) ----
    prep_kernel<<<400, 256, 0, stream>>>(
        ei, deg, E, batch, counts, N,
        Wk0, bk0, Wq0, bq0, Wv0, bv0, Ws0, cb0, Wf0, bf0,
        Wk1, bk1, Wq1, bq1, Wv1, bv1, Ws1, cb1, Wf1, bf1);
    scan1_kernel<<<NCHUNK, 256, 0, stream>>>(deg, rp1loc, psum, N);
    scan2_kernel<<<1, 256, 0, stream>>>(psum, NCHUNK);
    scan3_kernel<<<256, 256, 0, stream>>>(rp1loc, psum, rowptr, cursor, N);
    scatter_kernel<<<512, 256, 0, stream>>>(ei, cursor, col, E);

    const float invN = 1.0f / (float)N;
    const int projBlocks = ((N + 63) / 64) * 2;

    // ---- layer 0 ----
    proj_kernel<128, false><<<projBlocks, 256, 0, stream>>>(
        x, Wf0, bf0, nullptr, nullptr, Y2, QV, N);
    agg_kernel<<<2048, 256, 0, stream>>>(rowptr, col, Y2, QV, batch,
                                         H, stats0, gsumy0, N);
    prep_affine_kernel<<<1, 64, 0, stream>>>(stats0, g0, be0, Aaff, Baff, invN);

    // ---- layer 1 (BN affine applied while staging H) ----
    proj_kernel<64, true><<<projBlocks, 256, 0, stream>>>(
        H, Wf1, bf1, Aaff, Baff, Y2, QV, N);
    agg_kernel<<<2048, 256, 0, stream>>>(rowptr, col, Y2, QV, batch,
                                         H, stats1, gsumy1, N);

    // ---- head ----
    head1_kernel<<<128, 128, 0, stream>>>(gsumy0, gsumy1, counts,
                                          stats0, stats1, g0, be0, g1, be1,
                                          Wh0, bh0, t0, hstat0, invN);
    head2_kernel<<<128, 64, 0, stream>>>(t0, hstat0, gh0, beh0, Wh1, bh1, t1, hstat1);
    head3_kernel<<<128, 64, 0, stream>>>(t1, hstat1, gh1, beh1, Wc, bc, (float*)d_out);
}

// Round 9
// 647.865 us; speedup vs baseline: 2.0338x; 1.0030x over previous
//
#include <hip/hip_runtime.h>
#include <hip/hip_fp16.h>
#include <math.h>

#define EPS 1e-5f
#define N_GRAPHS 128

__device__ __forceinline__ float sigmoidf_(float x) {
    return __fdividef(1.0f, 1.0f + __expf(-x));
}

// ---------------------------------------------------------------------------
// Fused prep: block-range partition.
//  [0,256):  deg histogram      [256,320): fuse_w layer0 (K=128)
//  [320,384): fuse_w layer1 (K=64)        [384,400): per-graph counts
// ---------------------------------------------------------------------------
__device__ __forceinline__ void fuse_w_body(
    int b0, int blk, int tid,
    const float* __restrict__ Wk, const float* __restrict__ bk,
    const float* __restrict__ Wq, const float* __restrict__ bq,
    const float* __restrict__ Wv, const float* __restrict__ bv,
    const float* __restrict__ Ws, const float* __restrict__ cbv,
    float* __restrict__ Wf, float* __restrict__ bf, int K)
{
    int t = (blk - b0) * 256 + tid;
    int total = K * 256;
    for (int i = t; i < total; i += 64 * 256) {
        int k = i >> 8, c = i & 255;
        const float* W;
        int cc;
        if (c < 64)       { W = Wk; cc = c; }
        else if (c < 128) { W = Ws; cc = c - 64; }
        else { int j = c - 128; cc = j >> 1; W = (j & 1) ? Wv : Wq; }
        Wf[i] = W[k * 64 + cc];
    }
    if (t < 256) {
        int c = t;
        const float* b;
        int cc;
        if (c < 64)       { b = bk;  cc = c; }
        else if (c < 128) { b = cbv; cc = c - 64; }
        else { int j = c - 128; cc = j >> 1; b = (j & 1) ? bv : bq; }
        bf[t] = b[cc];
    }
}

__global__ __launch_bounds__(256) void prep_kernel(
    const int* __restrict__ ei, int* __restrict__ deg, int E,
    const int* __restrict__ batch, float* __restrict__ counts, int N,
    const float* __restrict__ Wk0, const float* __restrict__ bk0,
    const float* __restrict__ Wq0, const float* __restrict__ bq0,
    const float* __restrict__ Wv0, const float* __restrict__ bv0,
    const float* __restrict__ Ws0, const float* __restrict__ cb0,
    float* __restrict__ Wf0, float* __restrict__ bf0,
    const float* __restrict__ Wk1, const float* __restrict__ bk1,
    const float* __restrict__ Wq1, const float* __restrict__ bq1,
    const float* __restrict__ Wv1, const float* __restrict__ bv1,
    const float* __restrict__ Ws1, const float* __restrict__ cb1,
    float* __restrict__ Wf1, float* __restrict__ bf1)
{
    const int blk = blockIdx.x;
    const int tid = threadIdx.x;
    if (blk < 256) {
        int t = blk * 256 + tid;
        for (int e = t; e < E; e += 256 * 256) atomicAdd(&deg[ei[E + e]], 1);
    } else if (blk < 320) {
        fuse_w_body(256, blk, tid, Wk0, bk0, Wq0, bq0, Wv0, bv0, Ws0, cb0,
                    Wf0, bf0, 128);
    } else if (blk < 384) {
        fuse_w_body(320, blk, tid, Wk1, bk1, Wq1, bq1, Wv1, bv1, Ws1, cb1,
                    Wf1, bf1, 64);
    } else {
        const int t = (blk - 384) * 256 + tid;
        const int T = 16 * 256;
        const int chunk = (N + T - 1) / T;
        const int a = t * chunk;
        const int b = min(N, a + chunk);
        int cur = -1;
        float c = 0.0f;
        for (int n = a; n < b; ++n) {
            int gi = batch[n];
            if (gi != cur) {
                if (cur >= 0) atomicAdd(&counts[cur], c);
                cur = gi;
                c = 0.0f;
            }
            c += 1.0f;
        }
        if (cur >= 0) atomicAdd(&counts[cur], c);
    }
}

// ---------------------------------------------------------------------------
// Projection: LDS-tiled fp32 GEMM, fused cols. Tile M=64 x N=128 (blockIdx&1).
// nb=0 -> fp32 [k|s] to Y2[N][128]; nb=1 -> fp16-packed (q,v) to QV[N][64].
// AFF: BN affine computed in-kernel from stats/g/be, applied while staging X.
// ---------------------------------------------------------------------------
template <int K, bool AFF>
__global__ __launch_bounds__(256) void proj_kernel(
    const float* __restrict__ X, const float* __restrict__ Wf,
    const float* __restrict__ bf,
    const float* __restrict__ stats, const float* __restrict__ g,
    const float* __restrict__ be, float invN,
    float* __restrict__ Y2, unsigned* __restrict__ QV, int N)
{
    __shared__ __attribute__((aligned(16))) float As[16][72];
    __shared__ __attribute__((aligned(16))) float Bs[16][128];
    const int tid = threadIdx.x;
    const int nb = blockIdx.x & 1;
    const int n0 = (blockIdx.x >> 1) * 64;
    const int cg = tid & 31;
    const int mg = tid >> 5;
    const int ar = tid >> 2, akq = (tid & 3) * 4;
    const int bk_ = tid >> 4, bcol = (tid & 15) * 8;

    float acc[8][4];
#pragma unroll
    for (int r = 0; r < 8; ++r)
#pragma unroll
        for (int j = 0; j < 4; ++j) acc[r][j] = 0.0f;

    for (int k0 = 0; k0 < K; k0 += 16) {
        float4 av4 = make_float4(0.f, 0.f, 0.f, 0.f);
        int row = n0 + ar;
        if (row < N) av4 = *(const float4*)&X[(size_t)row * K + k0 + akq];
        if constexpr (AFF) {
            float a4[4], b4[4];
#pragma unroll
            for (int i = 0; i < 4; ++i) {
                int c = k0 + akq + i;
                float m = stats[c] * invN;
                float vv = stats[64 + c] * invN - m * m;
                float rs = rsqrtf(vv + EPS) * g[c];
                a4[i] = rs;
                b4[i] = be[c] - m * rs;
            }
            av4.x = fmaf(av4.x, a4[0], b4[0]);
            av4.y = fmaf(av4.y, a4[1], b4[1]);
            av4.z = fmaf(av4.z, a4[2], b4[2]);
            av4.w = fmaf(av4.w, a4[3], b4[3]);
        }
        const float4 b0 = *(const float4*)&Wf[(size_t)(k0 + bk_) * 256 + nb * 128 + bcol];
        const float4 b1 = *(const float4*)&Wf[(size_t)(k0 + bk_) * 256 + nb * 128 + bcol + 4];
        __syncthreads();
        As[akq + 0][ar] = av4.x;
        As[akq + 1][ar] = av4.y;
        As[akq + 2][ar] = av4.z;
        As[akq + 3][ar] = av4.w;
        *(float4*)&Bs[bk_][bcol] = b0;
        *(float4*)&Bs[bk_][bcol + 4] = b1;
        __syncthreads();
#pragma unroll
        for (int kk = 0; kk < 16; ++kk) {
            float4 a0 = *(const float4*)&As[kk][8 * mg];
            float4 a1 = *(const float4*)&As[kk][8 * mg + 4];
            float4 bv = *(const float4*)&Bs[kk][4 * cg];
            float am[8] = {a0.x, a0.y, a0.z, a0.w, a1.x, a1.y, a1.z, a1.w};
#pragma unroll
            for (int r = 0; r < 8; ++r) {
                acc[r][0] = fmaf(am[r], bv.x, acc[r][0]);
                acc[r][1] = fmaf(am[r], bv.y, acc[r][1]);
                acc[r][2] = fmaf(am[r], bv.z, acc[r][2]);
                acc[r][3] = fmaf(am[r], bv.w, acc[r][3]);
            }
        }
    }

    float4 bias;
    bias.x = bf[nb * 128 + 4 * cg + 0];
    bias.y = bf[nb * 128 + 4 * cg + 1];
    bias.z = bf[nb * 128 + 4 * cg + 2];
    bias.w = bf[nb * 128 + 4 * cg + 3];
    const int nn = min(64, N - n0);
    if (nb == 0) {
#pragma unroll
        for (int r = 0; r < 8; ++r) {
            int row = 8 * mg + r;
            if (row < nn) {
                float4 o;
                o.x = acc[r][0] + bias.x;
                o.y = acc[r][1] + bias.y;
                o.z = acc[r][2] + bias.z;
                o.w = acc[r][3] + bias.w;
                *(float4*)&Y2[(size_t)(n0 + row) * 128 + 4 * cg] = o;
            }
        }
    } else {
#pragma unroll
        for (int r = 0; r < 8; ++r) {
            int row = 8 * mg + r;
            if (row < nn) {
                __half2 p0 = __floats2half2_rn(acc[r][0] + bias.x, acc[r][1] + bias.y);
                __half2 p1 = __floats2half2_rn(acc[r][2] + bias.z, acc[r][3] + bias.w);
                uint2 u;
                u.x = *reinterpret_cast<unsigned*>(&p0);
                u.y = *reinterpret_cast<unsigned*>(&p1);
                *(uint2*)&QV[(size_t)(n0 + row) * 64 + 2 * cg] = u;
            }
        }
    }
}

// ---------------------------------------------------------------------------
// CSR scans + scatter.
// ---------------------------------------------------------------------------
__global__ __launch_bounds__(256) void scan1_kernel(
    const int* __restrict__ deg, int* __restrict__ rp1loc,
    int* __restrict__ psum, int N)
{
    __shared__ int s[256];
    const int b = blockIdx.x;
    const int base = b * 1024;
    const int t = threadIdx.x;
    int v[4], sum = 0;
#pragma unroll
    for (int i = 0; i < 4; ++i) {
        int idx = base + t * 4 + i;
        v[i] = (idx < N) ? deg[idx] : 0;
        sum += v[i];
    }
    s[t] = sum;
    __syncthreads();
    for (int off = 1; off < 256; off <<= 1) {
        int x = (t >= off) ? s[t - off] : 0;
        __syncthreads();
        s[t] += x;
        __syncthreads();
    }
    int run = s[t] - sum;
#pragma unroll
    for (int i = 0; i < 4; ++i) {
        run += v[i];
        int idx = base + t * 4 + i;
        if (idx < N) rp1loc[idx] = run;
    }
    if (t == 255) psum[b] = s[255];
}

__global__ __launch_bounds__(256) void scan2_kernel(int* __restrict__ psum, int NBLK)
{
    __shared__ int s[256];
    int t = threadIdx.x;
    int c = (t < NBLK) ? psum[t] : 0;
    s[t] = c;
    __syncthreads();
    for (int off = 1; off < 256; off <<= 1) {
        int x = (t >= off) ? s[t - off] : 0;
        __syncthreads();
        s[t] += x;
        __syncthreads();
    }
    if (t < NBLK) psum[t] = s[t] - c;
}

__global__ __launch_bounds__(256) void scan3_kernel(
    const int* __restrict__ rp1loc, const int* __restrict__ psum,
    int* __restrict__ rowptr, int* __restrict__ cursor, int N)
{
    int t = blockIdx.x * 256 + threadIdx.x;
    int T = gridDim.x * 256;
    for (int i = t; i < N; i += T) {
        rowptr[i + 1] = rp1loc[i] + psum[i >> 10];
        cursor[i] = (i == 0) ? 0 : rp1loc[i - 1] + psum[(i - 1) >> 10];
    }
    if (t == 0) rowptr[0] = 0;
}

__global__ __launch_bounds__(256) void scatter_kernel(
    const int* __restrict__ ei, int* __restrict__ cursor,
    int* __restrict__ col, int E)
{
    int t = blockIdx.x * 256 + threadIdx.x;
    int T = gridDim.x * 256;
    for (int e = t; e < E; e += T) {
        int d = ei[E + e];
        int pos = atomicAdd(&cursor[d], 1);
        col[pos] = ei[e];
    }
}

// ---------------------------------------------------------------------------
// Aggregation v7: contiguous node chunk per wave. col indices read at
// WAVE-UNIFORM addresses (scalar s_load path) and forced to SGPRs via
// readfirstlane -> QV gather is saddr-form global_load_dword with zero
// per-edge VGPR address math, no ds_bpermute. ~8 VALU/edge.
// Fuses sigmoid + BN channel stats + per-graph raw-y sums.
// ---------------------------------------------------------------------------
__global__ __launch_bounds__(256) void agg_kernel(
    const int* __restrict__ rowptr, const int* __restrict__ col,
    const float* __restrict__ Y2, const unsigned* __restrict__ QV,
    const int* __restrict__ batch,
    float* __restrict__ H, float* __restrict__ stats,
    float* __restrict__ gsumy, int N)
{
    const int tid = threadIdx.x;
    const int lane = tid & 63;
    const int wid = __builtin_amdgcn_readfirstlane(
        (int)((blockIdx.x * blockDim.x + tid) >> 6));
    const int NW = (gridDim.x * blockDim.x) >> 6;
    const int chunk = (N + NW - 1) / NW;
    const int nA = wid * chunk;
    const int nB = min(N, nA + chunk);
    const float L2E = 1.44269504f;

    float st1 = 0.0f, st2 = 0.0f;
    float gacc = 0.0f;
    int cur = -1;

    for (int n = nA; n < nB; ++n) {
        const int r0 = __builtin_amdgcn_readfirstlane(rowptr[n]);
        const int r1 = __builtin_amdgcn_readfirstlane(rowptr[n + 1]);
        const float* __restrict__ yrow = Y2 + (size_t)n * 128;
        float kk = yrow[lane];
        float acc = yrow[64 + lane];
        const float nkl = kk * (-L2E);

        int e = r0;
        for (; e + 4 <= r1; e += 4) {
            // uniform-address col reads -> scalar loads; indices to SGPRs
            int s0 = __builtin_amdgcn_readfirstlane(col[e]);
            int s1 = __builtin_amdgcn_readfirstlane(col[e + 1]);
            int s2 = __builtin_amdgcn_readfirstlane(col[e + 2]);
            int s3 = __builtin_amdgcn_readfirstlane(col[e + 3]);
            unsigned u0 = QV[((size_t)s0 << 6) + lane];
            unsigned u1 = QV[((size_t)s1 << 6) + lane];
            unsigned u2 = QV[((size_t)s2 << 6) + lane];
            unsigned u3 = QV[((size_t)s3 << 6) + lane];
            float2 f0 = __half22float2(*reinterpret_cast<__half2*>(&u0));
            float2 f1 = __half22float2(*reinterpret_cast<__half2*>(&u1));
            float2 f2 = __half22float2(*reinterpret_cast<__half2*>(&u2));
            float2 f3 = __half22float2(*reinterpret_cast<__half2*>(&u3));
            float e0 = __builtin_amdgcn_exp2f(fmaf(f0.x, -L2E, nkl));
            float e1 = __builtin_amdgcn_exp2f(fmaf(f1.x, -L2E, nkl));
            float e2 = __builtin_amdgcn_exp2f(fmaf(f2.x, -L2E, nkl));
            float e3 = __builtin_amdgcn_exp2f(fmaf(f3.x, -L2E, nkl));
            acc = fmaf(__builtin_amdgcn_rcpf(1.0f + e0), f0.y, acc);
            acc = fmaf(__builtin_amdgcn_rcpf(1.0f + e1), f1.y, acc);
            acc = fmaf(__builtin_amdgcn_rcpf(1.0f + e2), f2.y, acc);
            acc = fmaf(__builtin_amdgcn_rcpf(1.0f + e3), f3.y, acc);
        }
        for (; e < r1; ++e) {
            int s0 = __builtin_amdgcn_readfirstlane(col[e]);
            unsigned u0 = QV[((size_t)s0 << 6) + lane];
            float2 f0 = __half22float2(*reinterpret_cast<__half2*>(&u0));
            float e0 = __builtin_amdgcn_exp2f(fmaf(f0.x, -L2E, nkl));
            acc = fmaf(__builtin_amdgcn_rcpf(1.0f + e0), f0.y, acc);
        }

        float y = __builtin_amdgcn_rcpf(
            1.0f + __builtin_amdgcn_exp2f(acc * (-L2E)));
        H[(size_t)n * 64 + lane] = y;
        st1 += y;
        st2 += y * y;
        int gi = __builtin_amdgcn_readfirstlane(batch[n]);
        if (gi != cur) {
            if (cur >= 0) atomicAdd(&gsumy[cur * 64 + lane], gacc);
            gacc = 0.0f;
            cur = gi;
        }
        gacc += y;
    }
    if (cur >= 0) atomicAdd(&gsumy[cur * 64 + lane], gacc);

    __shared__ float red1[4][64], red2[4][64];
    const int w = tid >> 6;
    red1[w][lane] = st1;
    red2[w][lane] = st2;
    __syncthreads();
    if (tid < 64) {
        float a = red1[0][lane] + red1[1][lane] + red1[2][lane] + red1[3][lane];
        float c = red2[0][lane] + red2[1][lane] + red2[2][lane] + red2[3][lane];
        atomicAdd(&stats[lane], a);
        atomicAdd(&stats[64 + lane], c);
    }
}

// ---------------------------------------------------------------------------
// Head 1: reconstruct BN'd per-graph sums from raw-y sums via the affine
//   sum_v = rs*sum_y + cnt*(be - m*rs),  mean = sum_v / max(cnt,1)
// ---------------------------------------------------------------------------
__global__ __launch_bounds__(128) void head1_kernel(
    const float* __restrict__ gsumy0, const float* __restrict__ gsumy1,
    const float* __restrict__ counts,
    const float* __restrict__ stats0, const float* __restrict__ stats1,
    const float* __restrict__ g0, const float* __restrict__ be0,
    const float* __restrict__ g1, const float* __restrict__ be1,
    const float* __restrict__ Wh0, const float* __restrict__ bh0,
    float* __restrict__ t0, float* __restrict__ hstat0, float invN)
{
    const int gr = blockIdx.x;
    const int o = threadIdx.x;
    __shared__ float feat[256];

    const float* st = (o < 64) ? stats0 : stats1;
    const float* gg = (o < 64) ? g0 : g1;
    const float* bb = (o < 64) ? be0 : be1;
    const float* gs = (o < 64) ? gsumy0 : gsumy1;
    int c = o & 63;
    float m = st[c] * invN;
    float var = st[64 + c] * invN - m * m;
    float rs = rsqrtf(var + EPS) * gg[c];
    float off = bb[c] - m * rs;
    float cnt = counts[gr];
    float sv = rs * gs[gr * 64 + c] + cnt * off;
    float inv = __fdividef(1.0f, fmaxf(cnt, 1.0f));
    feat[o] = sv * inv;
    feat[128 + o] = sv;
    __syncthreads();

    float acc = bh0[o];
    for (int j = 0; j < 256; ++j) acc = fmaf(feat[j], Wh0[j * 128 + o], acc);
    float y = sigmoidf_(acc);
    t0[gr * 128 + o] = y;
    atomicAdd(&hstat0[o], y);
    atomicAdd(&hstat0[128 + o], y * y);
}

__global__ __launch_bounds__(64) void head2_kernel(
    const float* __restrict__ t0, const float* __restrict__ hstat0,
    const float* __restrict__ gh0, const float* __restrict__ beh0,
    const float* __restrict__ Wh1, const float* __restrict__ bh1,
    float* __restrict__ t1, float* __restrict__ hstat1)
{
    const int gr = blockIdx.x;
    const int o = threadIdx.x;
    __shared__ float bn0[128];
    const float invG = 1.0f / (float)N_GRAPHS;
    for (int j = o; j < 128; j += 64) {
        float m = hstat0[j] * invG;
        float v = hstat0[128 + j] * invG - m * m;
        bn0[j] = (t0[gr * 128 + j] - m) * rsqrtf(v + EPS) * gh0[j] + beh0[j];
    }
    __syncthreads();
    float acc = bh1[o];
    for (int j = 0; j < 128; ++j) acc = fmaf(bn0[j], Wh1[j * 64 + o], acc);
    float y = sigmoidf_(acc);
    t1[gr * 64 + o] = y;
    atomicAdd(&hstat1[o], y);
    atomicAdd(&hstat1[64 + o], y * y);
}

__global__ __launch_bounds__(64) void head3_kernel(
    const float* __restrict__ t1, const float* __restrict__ hstat1,
    const float* __restrict__ gh1, const float* __restrict__ beh1,
    const float* __restrict__ Wc, const float* __restrict__ bc,
    float* __restrict__ out)
{
    const int gr = blockIdx.x;
    const int o = threadIdx.x;
    const float invG = 1.0f / (float)N_GRAPHS;
    float m = hstat1[o] * invG;
    float v = hstat1[64 + o] * invG - m * m;
    float b = (t1[gr * 64 + o] - m) * rsqrtf(v + EPS) * gh1[o] + beh1[o];
    float p0 = b * Wc[o * 2];
    float p1 = b * Wc[o * 2 + 1];
#pragma unroll
    for (int off = 32; off > 0; off >>= 1) {
        p0 += __shfl_down(p0, off);
        p1 += __shfl_down(p1, off);
    }
    if (o == 0) {
        out[gr * 2] = p0 + bc[0];
        out[gr * 2 + 1] = p1 + bc[1];
    }
}

// ---------------------------------------------------------------------------
extern "C" void kernel_launch(void* const* d_in, const int* in_sizes, int n_in,
                              void* d_out, int out_size, void* d_ws, size_t ws_size,
                              hipStream_t stream)
{
    const float* x     = (const float*)d_in[0];
    const int*   ei    = (const int*)d_in[1];
    const int*   batch = (const int*)d_in[2];
    const int N = in_sizes[2];
    const int E = in_sizes[1] / 2;
    const int NCHUNK = (N + 1023) / 1024;

    const float *Wk0 = (const float*)d_in[3],  *bk0 = (const float*)d_in[4];
    const float *Wq0 = (const float*)d_in[5],  *bq0 = (const float*)d_in[6];
    const float *Wv0 = (const float*)d_in[7],  *bv0 = (const float*)d_in[8];
    const float *Ws0 = (const float*)d_in[9],  *cb0 = (const float*)d_in[10];
    const float *g0  = (const float*)d_in[11], *be0 = (const float*)d_in[12];
    const float *Wk1 = (const float*)d_in[13], *bk1 = (const float*)d_in[14];
    const float *Wq1 = (const float*)d_in[15], *bq1 = (const float*)d_in[16];
    const float *Wv1 = (const float*)d_in[17], *bv1 = (const float*)d_in[18];
    const float *Ws1 = (const float*)d_in[19], *cb1 = (const float*)d_in[20];
    const float *g1  = (const float*)d_in[21], *be1 = (const float*)d_in[22];
    const float *Wh0 = (const float*)d_in[23], *bh0 = (const float*)d_in[24];
    const float *gh0 = (const float*)d_in[25], *beh0 = (const float*)d_in[26];
    const float *Wh1 = (const float*)d_in[27], *bh1 = (const float*)d_in[28];
    const float *gh1 = (const float*)d_in[29], *beh1 = (const float*)d_in[30];
    const float *Wc  = (const float*)d_in[31], *bc  = (const float*)d_in[32];

    float*    ws = (float*)d_ws;
    float*    Y2 = ws;                          // N*128 fp32 [k|s]
    unsigned* QV = (unsigned*)(Y2 + (size_t)N * 128);  // N*64 packed fp16 q|v
    float*    H  = (float*)(QV + (size_t)N * 64);      // N*64 fp32 (raw y)
    int*   col     = (int*)(H + (size_t)N * 64);       // E
    int*   rowptr  = col + E;             // N+1
    int*   rp1loc  = rowptr + N + 1;      // N
    int*   cursor  = rp1loc + N;          // N
    int*   psum    = cursor + N;          // 256
    float* Wf0  = (float*)(psum + 256);   // 128*256
    float* bf0  = Wf0 + 128 * 256;        // 256
    float* Wf1  = bf0 + 256;              // 64*256
    float* bf1  = Wf1 + 64 * 256;         // 256
    int*   deg     = (int*)(bf1 + 256);   // N    <-- zero zone starts here
    float* gsumy0 = (float*)(deg + N);    // 128*64
    float* gsumy1 = gsumy0 + 128 * 64;    // 128*64
    float* counts = gsumy1 + 128 * 64;    // 128
    float* stats0 = counts + 128;         // 128
    float* stats1 = stats0 + 128;         // 128
    float* hstat0 = stats1 + 128;         // 256
    float* hstat1 = hstat0 + 256;         // 128
    size_t zbytes = (size_t)N * sizeof(int) +
                    (size_t)(128 * 64 * 2 + 128 * 3 + 256 + 128) * sizeof(float);
    float* t0 = hstat1 + 128;             // 128*128
    float* t1 = t0 + 128 * 128;           // 128*64

    hipMemsetAsync(deg, 0, zbytes, stream);

    // ---- fused prep (deg + counts + weight fusion) ----
    prep_kernel<<<400, 256, 0, stream>>>(
        ei, deg, E, batch, counts, N,
        Wk0, bk0, Wq0, bq0, Wv0, bv0, Ws0, cb0, Wf0, bf0,
        Wk1, bk1, Wq1, bq1, Wv1, bv1, Ws1, cb1, Wf1, bf1);
    scan1_kernel<<<NCHUNK, 256, 0, stream>>>(deg, rp1loc, psum, N);
    scan2_kernel<<<1, 256, 0, stream>>>(psum, NCHUNK);
    scan3_kernel<<<256, 256, 0, stream>>>(rp1loc, psum, rowptr, cursor, N);
    scatter_kernel<<<512, 256, 0, stream>>>(ei, cursor, col, E);

    const float invN = 1.0f / (float)N;
    const int projBlocks = ((N + 63) / 64) * 2;

    // ---- layer 0 ----
    proj_kernel<128, false><<<projBlocks, 256, 0, stream>>>(
        x, Wf0, bf0, nullptr, nullptr, nullptr, invN, Y2, QV, N);
    agg_kernel<<<2048, 256, 0, stream>>>(rowptr, col, Y2, QV, batch,
                                         H, stats0, gsumy0, N);

    // ---- layer 1 (BN affine computed in-kernel from stats0) ----
    proj_kernel<64, true><<<projBlocks, 256, 0, stream>>>(
        H, Wf1, bf1, stats0, g0, be0, invN, Y2, QV, N);
    agg_kernel<<<2048, 256, 0, stream>>>(rowptr, col, Y2, QV, batch,
                                         H, stats1, gsumy1, N);

    // ---- head ----
    head1_kernel<<<128, 128, 0, stream>>>(gsumy0, gsumy1, counts,
                                          stats0, stats1, g0, be0, g1, be1,
                                          Wh0, bh0, t0, hstat0, invN);
    head2_kernel<<<128, 64, 0, stream>>>(t0, hstat0, gh0, beh0, Wh1, bh1, t1, hstat1);
    head3_kernel<<<128, 64, 0, stream>>>(t1, hstat1, gh1, beh1, Wc, bc, (float*)d_out);
}